// Round 6
// baseline (4340.927 us; speedup 1.0000x reference)
//
#include <hip/hip_runtime.h>
#include <math.h>

// ---------------- model dims ----------------
#define NB    8      // batch
#define E     256    // embed
#define LTOK  256    // tokens
#define DI    512    // inner dim
#define DS    16     // state dim
#define DTR   16     // dt rank
#define NC    32     // scan chunks
#define CL    8      // chunk length (LTOK/NC)
#define NBLK  512    // grid size (2 blocks/CU x 256 CUs)

__device__ __forceinline__ float gelu_f(float x) {
    return 0.5f * x * (1.0f + erff(x * 0.70710678118654752440f));
}
__device__ __forceinline__ float silu_f(float x) {
    return x / (1.0f + expf(-x));
}
__device__ __forceinline__ float softplus_f(float x) {
    return fmaxf(x, 0.0f) + log1pf(expf(-fabsf(x)));
}

// ---------------- grid barrier: monotonic counter, device-scope ----------------
// All NBLK blocks call with the same k (1,2,3,...). Bounded spin: on pathological
// non-co-residency it breaks (wrong answer, no hang).
__device__ __forceinline__ void gsync(unsigned* cnt, unsigned k) {
    __syncthreads();
    if (threadIdx.x == 0) {
        __threadfence();                       // release: publish this block's writes
        atomicAdd(cnt, 1u);                    // device-scope by default on HIP global
        unsigned target = k * (unsigned)NBLK;
        for (long spin = 0; spin < 1000000; ++spin) {
            if (atomicAdd(cnt, 0u) >= target) break;
            __builtin_amdgcn_s_sleep(2);
        }
        __threadfence();                       // acquire: invalidate caches for reads
    }
    __syncthreads();
}

// block-wide sum over 256 threads (4 waves). red = 4 floats of smem.
__device__ __forceinline__ float block_sum256(float x, float* red) {
#pragma unroll
    for (int off = 32; off > 0; off >>= 1) x += __shfl_down(x, off, 64);
    __syncthreads();
    if ((threadIdx.x & 63) == 0) red[threadIdx.x >> 6] = x;
    __syncthreads();
    return red[0] + red[1] + red[2] + red[3];
}

// ---------------- stage device functions ----------------

__device__ void time_emb_dev(const int* t, const float* w1, const float* b1,
                             const float* w2, const float* b2,
                             float* temb, int b, float* smem) {
    int e = threadIdx.x;
    float* hid = smem;
    float tf = (float)t[b];
    hid[e] = gelu_f(tf * w1[e] + b1[e]);
    __syncthreads();
    float acc = b2[e];
    for (int k = 0; k < E; ++k) acc = fmaf(hid[k], w2[k * E + e], acc);
    temb[b * E + e] = acc;
}

__device__ void gather_dev(const float* x, float* P, int vbi) {
    int idx = vbi * 256 + threadIdx.x;          // < 262144
    int k4 = idx & 127, m = idx >> 7;
    int b = m >> 8, l = m & 255, hh = l >> 4, ww = l & 15;
    int k = k4 * 4;
    int c = k >> 8, pq = k & 255, p = pq >> 4, q = pq & 15;
    float4 v = *(const float4*)&x[(((size_t)(b * 2 + c) * 256) + hh * 16 + p) * 256 + ww * 16 + q];
    *(float4*)&P[(size_t)m * 512 + k] = v;
}

// generic fp32 GEMM (NT) with register prefetch.
// BM=64, BN=64, BK=32, TM=4, TN=4, 256 threads.
__device__ void gemm_dev(const float* A, int lda, const float* Bw, int ldb,
                         float* C, int ldc, int K, int zstride,
                         int nx, int my, int z, float* smem) {
    const int tid = threadIdx.x;
    const int n0 = nx * 64, m0 = my * 64;
    const int kbase = z * K;
    float* Cz = C + (size_t)z * zstride;
    float (*As)[68] = (float(*)[68])smem;
    float (*Bs)[68] = (float(*)[68])(smem + 32 * 68);
    const int tx = tid & 15, ty = tid >> 4;
    const int srow = tid >> 3, sk4 = tid & 7;
    const float* Ap0 = A + (size_t)(m0 + srow) * lda + kbase + sk4 * 4;
    const float* Ap1 = Ap0 + (size_t)32 * lda;
    const float* Bp0 = Bw + (size_t)(n0 + srow) * ldb + kbase + sk4 * 4;
    const float* Bp1 = Bp0 + (size_t)32 * ldb;
    float4 pa0 = *(const float4*)Ap0, pa1 = *(const float4*)Ap1;
    float4 pb0 = *(const float4*)Bp0, pb1 = *(const float4*)Bp1;
    float acc[4][4] = {};
    const int T = K >> 5;
    for (int t = 0;; ++t) {
        As[sk4 * 4 + 0][srow] = pa0.x;  As[sk4 * 4 + 1][srow] = pa0.y;
        As[sk4 * 4 + 2][srow] = pa0.z;  As[sk4 * 4 + 3][srow] = pa0.w;
        As[sk4 * 4 + 0][srow + 32] = pa1.x;  As[sk4 * 4 + 1][srow + 32] = pa1.y;
        As[sk4 * 4 + 2][srow + 32] = pa1.z;  As[sk4 * 4 + 3][srow + 32] = pa1.w;
        Bs[sk4 * 4 + 0][srow] = pb0.x;  Bs[sk4 * 4 + 1][srow] = pb0.y;
        Bs[sk4 * 4 + 2][srow] = pb0.z;  Bs[sk4 * 4 + 3][srow] = pb0.w;
        Bs[sk4 * 4 + 0][srow + 32] = pb1.x;  Bs[sk4 * 4 + 1][srow + 32] = pb1.y;
        Bs[sk4 * 4 + 2][srow + 32] = pb1.z;  Bs[sk4 * 4 + 3][srow + 32] = pb1.w;
        __syncthreads();
        if (t + 1 < T) {
            int off = (t + 1) * 32;
            pa0 = *(const float4*)(Ap0 + off);
            pa1 = *(const float4*)(Ap1 + off);
            pb0 = *(const float4*)(Bp0 + off);
            pb1 = *(const float4*)(Bp1 + off);
        }
#pragma unroll
        for (int kk = 0; kk < 32; ++kk) {
            float4 av = *(const float4*)&As[kk][ty * 4];
            float4 bv = *(const float4*)&Bs[kk][tx * 4];
            float a[4] = {av.x, av.y, av.z, av.w};
            float b[4] = {bv.x, bv.y, bv.z, bv.w};
#pragma unroll
            for (int i = 0; i < 4; ++i)
#pragma unroll
                for (int j = 0; j < 4; ++j) acc[i][j] = fmaf(a[i], b[j], acc[i][j]);
        }
        if (t + 1 >= T) break;
        __syncthreads();
    }
    __syncthreads();
#pragma unroll
    for (int i = 0; i < 4; ++i) {
        int m = m0 + ty * 4 + i;
        *(float4*)&Cz[(size_t)m * ldc + n0 + tx * 4] =
            make_float4(acc[i][0], acc[i][1], acc[i][2], acc[i][3]);
    }
}

__device__ void ln_patch_dev(const float* part, const float* pb,
                             const float* pos, const float* temb,
                             const float* g, const float* bta,
                             float* h, float* hn, int m, float* smem) {
    int e = threadIdx.x;
    int b = m >> 8, l = m & 255;
    size_t o = (size_t)m * 256 + e;
    float v = (part[o] + part[524288 + o]) + (part[1048576 + o] + part[1572864 + o])
            + pb[e] + pos[l * 256 + e] + temb[b * 256 + e];
    h[o] = v;
    float mean = block_sum256(v, smem) * (1.0f / 256.0f);
    float dv = v - mean;
    float var = block_sum256(dv * dv, smem) * (1.0f / 256.0f);
    float rstd = rsqrtf(var + 1e-5f);
    hn[o] = dv * rstd * g[e] + bta[e];
}

__device__ void ln_res_dev(const float* part, const float* g, const float* bta,
                           float* h, float* hn, int do_ln, int m, float* smem) {
    int e = threadIdx.x;
    size_t o = (size_t)m * 256 + e;
    float v = (part[o] + part[524288 + o]) + (part[1048576 + o] + part[1572864 + o]) + h[o];
    h[o] = v;
    if (do_ln) {
        float mean = block_sum256(v, smem) * (1.0f / 256.0f);
        float dv = v - mean;
        float var = block_sum256(dv * dv, smem) * (1.0f / 256.0f);
        float rstd = rsqrtf(var + 1e-5f);
        hn[o] = dv * rstd * g[e] + bta[e];
    }
}

// x_proj GEMM with fused conv+silu A-staging; per-slice K = 64
__device__ void xproj_dev(const float* xz, const float* xpw,
                          const float* cw, const float* cb,
                          float* partx, int my, int z, float* smem) {
    const int tid = threadIdx.x;
    const int m0 = my * 32;
    const int kb = z * 64;
    float (*As)[36] = (float(*)[36])smem;
    float (*Bs)[52] = (float(*)[52])(smem + 16 * 36);
    const int tx = tid & 15, ty = tid >> 4;
    float acc[2][3] = {};
    for (int k0 = 0; k0 < 64; k0 += 16) {
#pragma unroll
        for (int idx = tid; idx < 512; idx += 256) {
            int mm = idx >> 4, kk = idx & 15;
            int d = kb + k0 + kk;
            int m = m0 + mm;
            int l = m & 255;
            float4 w4 = *(const float4*)&cw[d * 4];
            float a = cb[d];
            const float* col = xz + (size_t)m * 1024 + d;
            if (l >= 3) {
                a = fmaf(col[-3072], w4.x, a);
                a = fmaf(col[-2048], w4.y, a);
                a = fmaf(col[-1024], w4.z, a);
                a = fmaf(col[0],     w4.w, a);
            } else {
                if (l >= 2) a = fmaf(col[-2048], w4.y, a);
                if (l >= 1) a = fmaf(col[-1024], w4.z, a);
                a = fmaf(col[0], w4.w, a);
            }
            As[kk][mm] = silu_f(a);
        }
#pragma unroll
        for (int idx = tid; idx < 768; idx += 256) {
            int nn = idx >> 4, kk = idx & 15;
            Bs[kk][nn] = xpw[(size_t)nn * 512 + kb + k0 + kk];
        }
        __syncthreads();
#pragma unroll
        for (int kk = 0; kk < 16; ++kk) {
            float a0 = As[kk][ty * 2 + 0];
            float a1 = As[kk][ty * 2 + 1];
            float b0 = Bs[kk][tx * 3 + 0];
            float b1 = Bs[kk][tx * 3 + 1];
            float b2 = Bs[kk][tx * 3 + 2];
            acc[0][0] = fmaf(a0, b0, acc[0][0]);
            acc[0][1] = fmaf(a0, b1, acc[0][1]);
            acc[0][2] = fmaf(a0, b2, acc[0][2]);
            acc[1][0] = fmaf(a1, b0, acc[1][0]);
            acc[1][1] = fmaf(a1, b1, acc[1][1]);
            acc[1][2] = fmaf(a1, b2, acc[1][2]);
        }
        __syncthreads();
    }
    size_t zb = (size_t)z * 98304;
#pragma unroll
    for (int i = 0; i < 2; ++i) {
        int m = m0 + ty * 2 + i;
#pragma unroll
        for (int j = 0; j < 3; ++j)
            partx[zb + (size_t)m * 48 + tx * 3 + j] = acc[i][j];
    }
}

// load dbc tile (CL x 48) = sum of 8 x_proj partials
__device__ __forceinline__ void load_dbc(const float* partx, int b, int c,
                                         float (*dbcS)[48]) {
    for (int idx = threadIdx.x; idx < CL * 48; idx += 256) {
        int r = idx / 48, col = idx % 48;
        size_t o = (size_t)(b * LTOK + c * CL + r) * 48 + col;
        float s = 0.0f;
#pragma unroll
        for (int z = 0; z < 8; ++z) s += partx[(size_t)z * 98304 + o];
        dbcS[r][col] = s;
    }
}

__device__ void scan1_dev(const float* partx, const float* xz,
                          const float* cw, const float* cb,
                          const float* dtw, const float* dtb, const float* alog,
                          float* hpart, float* pprod,
                          int c, int b, int z, float* smem) {
    int d = z * 256 + threadIdx.x;
    float (*dbcS)[48] = (float(*)[48])smem;
    load_dbc(partx, b, c, dbcS);
    float wv[16], Av[16];
#pragma unroll
    for (int s4 = 0; s4 < 16; s4 += 4) {
        float4 t1 = *(const float4*)(dtw + d * 16 + s4);
        wv[s4] = t1.x; wv[s4 + 1] = t1.y; wv[s4 + 2] = t1.z; wv[s4 + 3] = t1.w;
        float4 t2 = *(const float4*)(alog + d * 16 + s4);
        Av[s4] = -expf(t2.x); Av[s4 + 1] = -expf(t2.y); Av[s4 + 2] = -expf(t2.z); Av[s4 + 3] = -expf(t2.w);
    }
    float bv = dtb[d];
    float4 cwv = *(const float4*)&cw[d * 4];
    float cbv = cb[d];
    const float* colp = xz + ((size_t)(b * LTOK + c * CL)) * 1024 + d;
    float x0 = 0.f, x1 = 0.f, x2 = 0.f;
    if (c > 0) { x0 = colp[-3072]; x1 = colp[-2048]; x2 = colp[-1024]; }
    float h[16] = {}, P[16];
#pragma unroll
    for (int s = 0; s < 16; ++s) P[s] = 1.0f;
    __syncthreads();
    for (int r = 0; r < CL; ++r) {
        float xin = colp[r * 1024];
        float uv = cbv;
        uv = fmaf(x0, cwv.x, uv);
        uv = fmaf(x1, cwv.y, uv);
        uv = fmaf(x2, cwv.z, uv);
        uv = fmaf(xin, cwv.w, uv);
        uv = silu_f(uv);
        x0 = x1; x1 = x2; x2 = xin;
        float pre = bv;
#pragma unroll
        for (int j = 0; j < 16; ++j) pre = fmaf(dbcS[r][j], wv[j], pre);
        float dt = softplus_f(pre);
        float du = dt * uv;
#pragma unroll
        for (int s = 0; s < 16; ++s) {
            float dA = expf(dt * Av[s]);
            h[s] = fmaf(dA, h[s], du * dbcS[r][16 + s]);
            P[s] *= dA;
        }
    }
    size_t base = ((size_t)((b * NC + c) * DI) + d) * 16;
#pragma unroll
    for (int s = 0; s < 16; ++s) { hpart[base + s] = h[s]; pprod[base + s] = P[s]; }
    __syncthreads();
}

__device__ void scan2_dev(const float* hpart, const float* pprod,
                          float* hinit, int vb) {
    if (vb < 256) {
        int idx = vb * 256 + threadIdx.x;   // b*8192 + d*16 + s
        int b = idx >> 13, ds = idx & 8191;
        float carry = 0.0f;
        for (int c = 0; c < NC; ++c) {
            size_t a = ((size_t)(b * NC + c)) * (DI * 16) + ds;
            hinit[a] = carry;
            carry = fmaf(pprod[a], carry, hpart[a]);
        }
    }
}

__device__ void scan3_dev(const float* partx, const float* xz,
                          const float* cw, const float* cb,
                          const float* dtw, const float* dtb,
                          const float* alog, const float* Dpv,
                          const float* hinit, float* yz,
                          int c, int b, int z, float* smem) {
    int d = z * 256 + threadIdx.x;
    float (*dbcS)[48] = (float(*)[48])smem;
    load_dbc(partx, b, c, dbcS);
    float wv[16], Av[16];
#pragma unroll
    for (int s4 = 0; s4 < 16; s4 += 4) {
        float4 t1 = *(const float4*)(dtw + d * 16 + s4);
        wv[s4] = t1.x; wv[s4 + 1] = t1.y; wv[s4 + 2] = t1.z; wv[s4 + 3] = t1.w;
        float4 t2 = *(const float4*)(alog + d * 16 + s4);
        Av[s4] = -expf(t2.x); Av[s4 + 1] = -expf(t2.y); Av[s4 + 2] = -expf(t2.z); Av[s4 + 3] = -expf(t2.w);
    }
    float bv = dtb[d];
    float Dv = Dpv[d];
    float4 cwv = *(const float4*)&cw[d * 4];
    float cbv = cb[d];
    float h[16];
    size_t base = ((size_t)((b * NC + c) * DI) + d) * 16;
#pragma unroll
    for (int s = 0; s < 16; ++s) h[s] = hinit[base + s];
    const float* colp = xz + ((size_t)(b * LTOK + c * CL)) * 1024 + d;
    const float* zrow = colp + 512;
    float* yrow = yz + ((size_t)(b * LTOK + c * CL)) * 512 + d;
    float x0 = 0.f, x1 = 0.f, x2 = 0.f;
    if (c > 0) { x0 = colp[-3072]; x1 = colp[-2048]; x2 = colp[-1024]; }
    __syncthreads();
    for (int r = 0; r < CL; ++r) {
        float xin = colp[r * 1024];
        float uv = cbv;
        uv = fmaf(x0, cwv.x, uv);
        uv = fmaf(x1, cwv.y, uv);
        uv = fmaf(x2, cwv.z, uv);
        uv = fmaf(xin, cwv.w, uv);
        uv = silu_f(uv);
        x0 = x1; x1 = x2; x2 = xin;
        float pre = bv;
#pragma unroll
        for (int j = 0; j < 16; ++j) pre = fmaf(dbcS[r][j], wv[j], pre);
        float dt = softplus_f(pre);
        float du = dt * uv;
        float y = uv * Dv;
#pragma unroll
        for (int s = 0; s < 16; ++s) {
            float dA = expf(dt * Av[s]);
            h[s] = fmaf(dA, h[s], du * dbcS[r][16 + s]);
            y = fmaf(h[s], dbcS[r][32 + s], y);
        }
        float zv = zrow[r * 1024];
        yrow[r * 512] = y * silu_f(zv);
    }
    __syncthreads();
}

// decoder convT 2x2 stride2 as GEMM + bias + gelu, register prefetch.
// BM in {32,64}, BN=64, BK=32, TM=BM/16, TN=4.
template <int BM, bool AROW>
__device__ void convt_dev(const float* A, const float* Wt, const float* bias,
                          float* out, int K, int N, int HW, int Wdim, int O,
                          int nx, int my, float* smem) {
    constexpr int TM = BM / 16;
    const int tid = threadIdx.x;
    const int n0 = nx * 64;
    const int m0 = my * BM;
    float (*As)[BM + 4] = (float(*)[BM + 4])smem;
    float (*Bs)[68] = (float(*)[68])(smem + 32 * (BM + 4));
    const int tx = tid & 15, ty = tid >> 4;
    float acc[TM][4] = {};
    const int T = K >> 5;
    float4 pa0, pa1;
    float pra[BM / 8];
    float prb[8];
    const int srow = tid >> 3, sk4 = tid & 7;
    const float* Ap0 = nullptr; const float* Ap1 = nullptr; const float* Ab = nullptr;
    if constexpr (AROW) {
        Ap0 = A + (size_t)(m0 + srow) * K + sk4 * 4;
        Ap1 = Ap0 + (size_t)32 * K;
        pa0 = *(const float4*)Ap0;
        if constexpr (BM == 64) pa1 = *(const float4*)Ap1;
    } else {
        int bb = m0 / HW, hw0 = m0 % HW;
        Ab = A + ((size_t)bb * K) * HW + hw0;
#pragma unroll
        for (int f = 0; f < BM / 8; ++f)
            pra[f] = Ab[(size_t)((tid >> 6) + 4 * f) * HW + (tid & 63)];
    }
#pragma unroll
    for (int f = 0; f < 8; ++f)
        prb[f] = Wt[(size_t)((tid >> 6) + 4 * f) * N + n0 + (tid & 63)];
    for (int t = 0;; ++t) {
        if constexpr (AROW) {
            As[sk4 * 4 + 0][srow] = pa0.x;  As[sk4 * 4 + 1][srow] = pa0.y;
            As[sk4 * 4 + 2][srow] = pa0.z;  As[sk4 * 4 + 3][srow] = pa0.w;
            if constexpr (BM == 64) {
                As[sk4 * 4 + 0][srow + 32] = pa1.x;  As[sk4 * 4 + 1][srow + 32] = pa1.y;
                As[sk4 * 4 + 2][srow + 32] = pa1.z;  As[sk4 * 4 + 3][srow + 32] = pa1.w;
            }
        } else {
#pragma unroll
            for (int f = 0; f < BM / 8; ++f)
                As[(tid >> 6) + 4 * f][tid & 63] = pra[f];
        }
#pragma unroll
        for (int f = 0; f < 8; ++f)
            Bs[(tid >> 6) + 4 * f][tid & 63] = prb[f];
        __syncthreads();
        if (t + 1 < T) {
            int off = (t + 1) * 32;
            if constexpr (AROW) {
                pa0 = *(const float4*)(Ap0 + off);
                if constexpr (BM == 64) pa1 = *(const float4*)(Ap1 + off);
            } else {
#pragma unroll
                for (int f = 0; f < BM / 8; ++f)
                    pra[f] = Ab[(size_t)(off + (tid >> 6) + 4 * f) * HW + (tid & 63)];
            }
#pragma unroll
            for (int f = 0; f < 8; ++f)
                prb[f] = Wt[(size_t)(off + (tid >> 6) + 4 * f) * N + n0 + (tid & 63)];
        }
#pragma unroll
        for (int kk = 0; kk < 32; ++kk) {
            float a[TM];
#pragma unroll
            for (int i = 0; i < TM; ++i) a[i] = As[kk][ty * TM + i];
            float4 bv = *(const float4*)&Bs[kk][tx * 4];
            float b[4] = {bv.x, bv.y, bv.z, bv.w};
#pragma unroll
            for (int i = 0; i < TM; ++i)
#pragma unroll
                for (int j = 0; j < 4; ++j) acc[i][j] = fmaf(a[i], b[j], acc[i][j]);
        }
        if (t + 1 >= T) break;
        __syncthreads();
    }
    __syncthreads();
    int Hdim = HW / Wdim;
#pragma unroll
    for (int i = 0; i < TM; ++i) {
        int m = m0 + ty * TM + i;
        int b = m / HW, hw = m % HW;
        int hh = hw / Wdim, ww = hw % Wdim;
#pragma unroll
        for (int j = 0; j < 4; ++j) {
            int n = n0 + tx * 4 + j;
            int o = n >> 2, p = (n >> 1) & 1, q = n & 1;
            out[(((size_t)(b * O + o)) * (2 * Hdim) + 2 * hh + p) * (size_t)(2 * Wdim) + 2 * ww + q] =
                gelu_f(acc[i][j] + bias[o]);
        }
    }
}

__device__ void dec4_dev(const float* d3, const float* w4, const float* b4,
                         float* out, int vb) {
    int pix = vb * 256 + threadIdx.x;   // 131072
    int b = pix >> 14, hw = pix & 16383;
    int hh = hw >> 7, ww = hw & 127;
    float bias = b4[0];
    float a0 = bias, a1 = bias, a2 = bias, a3 = bias;
    const float* xb = d3 + ((size_t)b * 32) * 16384 + hw;
#pragma unroll 8
    for (int c = 0; c < 32; ++c) {
        float v = xb[(size_t)c * 16384];
        float4 wv = *(const float4*)(w4 + c * 4);
        a0 = fmaf(v, wv.x, a0);
        a1 = fmaf(v, wv.y, a1);
        a2 = fmaf(v, wv.z, a2);
        a3 = fmaf(v, wv.w, a3);
    }
    size_t ob = ((size_t)b * 256 + 2 * hh) * 256 + 2 * ww;
    out[ob] = a0;
    out[ob + 1] = a1;
    out[ob + 256] = a2;
    out[ob + 257] = a3;
}

// ---------------- workspace layout (floats) ----------------
#define H_OFF     ((size_t)0)
#define HN_OFF    ((size_t)524288)
#define TEMB_OFF  ((size_t)1048576)
#define PART_OFF  ((size_t)1050624)   // 4 x 524288
#define XZ_OFF    ((size_t)3147776)   // 2097152
#define PARTX_OFF ((size_t)5244928)   // 8 x 98304
#define YZ_OFF    ((size_t)6031360)   // 1048576
#define HPART_OFF ((size_t)7079936)   // 2097152
#define PPROD_OFF ((size_t)9177088)   // 2097152
#define HINIT_OFF ((size_t)11274240)  // 2097152
#define CNT_OFF   ((size_t)13500416)  // barrier counter (uint), byte off = 54001664

struct MegaParams {
    const float* x; const int* t;
    const float* tw1; const float* tb1; const float* tw2; const float* tb2;
    const float* pw; const float* pb; const float* pos;
    const float* lng; const float* lnb;
    const float* ipw; const float* cw; const float* cb; const float* xpw;
    const float* dtw; const float* dtb; const float* alog; const float* Dp;
    const float* opw;
    const float* dw1; const float* db1; const float* dw2; const float* db2;
    const float* dw3; const float* db3; const float* dw4; const float* db4;
    float* ws; float* out;
};

// ---------------- the mega kernel: whole net, 512 blocks x 256 threads ----------------
__global__ __launch_bounds__(256, 2) void mega_kernel(MegaParams p) {
    __shared__ float smem[4352];
    const int vb = blockIdx.x;

    float* ws    = p.ws;
    float* H     = ws + H_OFF;
    float* HN    = ws + HN_OFF;
    float* TEMB  = ws + TEMB_OFF;
    float* PART  = ws + PART_OFF;
    float* XZ    = ws + XZ_OFF;
    float* P     = XZ;               // patch matrix alias
    float* PARTX = ws + PARTX_OFF;
    float* YZ    = ws + YZ_OFF;
    float* HPART = ws + HPART_OFF;
    float* PPROD = ws + PPROD_OFF;
    float* HINIT = ws + HINIT_OFF;
    float* D1    = YZ;               // aliases: disjoint lifetimes
    float* D2    = HPART;
    float* D3    = ws;
    unsigned* cnt = (unsigned*)(ws + CNT_OFF);
    unsigned bk = 0;                 // barrier sequence number

    // S0: time embedding (blocks 0..7) + patch gather (all blocks, 2 iters)
    if (vb < 8) time_emb_dev(p.t, p.tw1, p.tb1, p.tw2, p.tb2, TEMB, vb, smem);
    gather_dev(p.x, P, vb);
    gather_dev(p.x, P, vb + 512);
    gsync(cnt, ++bk);

    // S1: patch-embed GEMM partials: M=2048, N=256, K=512 split 4
    gemm_dev(P, 512, p.pw, 512, PART, 256, 128, 524288,
             vb & 3, (vb >> 2) & 31, vb >> 7, smem);
    gsync(cnt, ++bk);

    // S2: ln_patch over 2048 rows
    for (int i = 0; i < 4; ++i)
        ln_patch_dev(PART, p.pb, p.pos, TEMB, p.lng, p.lnb, H, HN, vb + 512 * i, smem);
    gsync(cnt, ++bk);

    for (int layer = 0; layer < 8; ++layer) {
        const float* ipwL  = p.ipw  + (size_t)layer * 1024 * E;
        const float* cwL   = p.cw   + (size_t)layer * DI * 4;
        const float* cbL   = p.cb   + (size_t)layer * DI;
        const float* xpwL  = p.xpw  + (size_t)layer * 48 * DI;
        const float* dtwL  = p.dtw  + (size_t)layer * DI * DTR;
        const float* dtbL  = p.dtb  + (size_t)layer * DI;
        const float* alogL = p.alog + (size_t)layer * DI * DS;
        const float* DpL   = p.Dp   + (size_t)layer * DI;
        const float* opwL  = p.opw  + (size_t)layer * E * DI;

        // in_proj: M=2048, N=1024, K=256 (virtual grid 16x32)
        gemm_dev(HN, 256, ipwL, 256, XZ, 1024, 256, 0,
                 vb & 15, vb >> 4, 0, smem);
        gsync(cnt, ++bk);

        // x_proj partials (conv+silu fused): virtual grid (64 my, 8 z)
        xproj_dev(XZ, xpwL, cwL, cbL, PARTX, vb & 63, vb >> 6, smem);
        gsync(cnt, ++bk);

        // scan phase 1: virtual grid (32 c, 8 b, 2 z)
        scan1_dev(PARTX, XZ, cwL, cbL, dtwL, dtbL, alogL, HPART, PPROD,
                  vb & 31, (vb >> 5) & 7, vb >> 8, smem);
        gsync(cnt, ++bk);

        // scan phase 2: 65536 elems on first 256 blocks
        scan2_dev(HPART, PPROD, HINIT, vb);
        gsync(cnt, ++bk);

        // scan phase 3
        scan3_dev(PARTX, XZ, cwL, cbL, dtwL, dtbL, alogL, DpL, HINIT, YZ,
                  vb & 31, (vb >> 5) & 7, vb >> 8, smem);
        gsync(cnt, ++bk);

        // out_proj partials: M=2048, N=256, K=512 split 4
        gemm_dev(YZ, 512, opwL, 512, PART, 256, 128, 524288,
                 vb & 3, (vb >> 2) & 31, vb >> 7, smem);
        gsync(cnt, ++bk);

        // residual + LN
        int nl = (layer < 7) ? (layer + 1) : 0;
        for (int i = 0; i < 4; ++i)
            ln_res_dev(PART, p.lng + (size_t)nl * E, p.lnb + (size_t)nl * E,
                       H, HN, (layer < 7) ? 1 : 0, vb + 512 * i, smem);
        gsync(cnt, ++bk);
    }

    // decoder
    convt_dev<32, true>(H, p.dw1, p.db1, D1, 256, 512, 256, 16, 128,
                        vb & 7, vb >> 3, smem);
    gsync(cnt, ++bk);
    convt_dev<64, false>(D1, p.dw2, p.db2, D2, 128, 256, 1024, 32, 64,
                         vb & 3, vb >> 2, smem);
    gsync(cnt, ++bk);
    for (int i = 0; i < 2; ++i) {
        int vbb = vb + 512 * i;
        convt_dev<64, false>(D2, p.dw3, p.db3, D3, 64, 128, 4096, 64, 32,
                             vbb & 1, vbb >> 1, smem);
        __syncthreads();
    }
    gsync(cnt, ++bk);
    dec4_dev(D3, p.dw4, p.db4, p.out, vb);
}

extern "C" void kernel_launch(void* const* d_in, const int* in_sizes, int n_in,
                              void* d_out, int out_size, void* d_ws, size_t ws_size,
                              hipStream_t stream) {
    (void)in_sizes; (void)n_in; (void)out_size; (void)ws_size;
    MegaParams p;
    p.x    = (const float*)d_in[0];
    p.t    = (const int*)d_in[1];
    p.tw1  = (const float*)d_in[2];
    p.tb1  = (const float*)d_in[3];
    p.tw2  = (const float*)d_in[4];
    p.tb2  = (const float*)d_in[5];
    p.pw   = (const float*)d_in[6];
    p.pb   = (const float*)d_in[7];
    p.pos  = (const float*)d_in[8];
    p.lng  = (const float*)d_in[9];
    p.lnb  = (const float*)d_in[10];
    p.ipw  = (const float*)d_in[11];
    p.cw   = (const float*)d_in[12];
    p.cb   = (const float*)d_in[13];
    p.xpw  = (const float*)d_in[14];
    p.dtw  = (const float*)d_in[15];
    p.dtb  = (const float*)d_in[16];
    p.alog = (const float*)d_in[17];
    p.Dp   = (const float*)d_in[18];
    p.opw  = (const float*)d_in[19];
    p.dw1  = (const float*)d_in[20];
    p.db1  = (const float*)d_in[21];
    p.dw2  = (const float*)d_in[22];
    p.db2  = (const float*)d_in[23];
    p.dw3  = (const float*)d_in[24];
    p.db3  = (const float*)d_in[25];
    p.dw4  = (const float*)d_in[26];
    p.db4  = (const float*)d_in[27];
    p.ws   = (float*)d_ws;
    p.out  = (float*)d_out;

    // zero the barrier counter region (async memset is graph-capturable)
    hipMemsetAsync((char*)d_ws + CNT_OFF * sizeof(float), 0, 256, stream);
    hipLaunchKernelGGL(mega_kernel, dim3(NBLK), dim3(256), 0, stream, p);
}

// Round 8
// 1260.142 us; speedup vs baseline: 3.4448x; 3.4448x over previous
//
#include <hip/hip_runtime.h>
#include <math.h>

// ---------------- model dims ----------------
#define NB    8
#define E     256
#define LTOK  256
#define DI    512
#define DS    16
#define DTR   16
#define NC    32     // scan chunks
#define CL    8      // chunk length

__device__ __forceinline__ float gelu_f(float x) {
    return 0.5f * x * (1.0f + erff(x * 0.70710678118654752440f));
}
__device__ __forceinline__ float silu_f(float x) {
    return x / (1.0f + expf(-x));
}
__device__ __forceinline__ float softplus_f(float x) {
    return fmaxf(x, 0.0f) + log1pf(expf(-fabsf(x)));
}

// ============ patch-embed GEMM (gather fused) + time-emb on 8 blocks ============
// grid (4, 32, 4), 256 thr. C partials: PART[z][2048][256]. K=512 split 4.
__global__ __launch_bounds__(256) void patch_gemm(
    const float* __restrict__ x, const float* __restrict__ pw,
    const int* __restrict__ t,
    const float* __restrict__ tw1, const float* __restrict__ tb1,
    const float* __restrict__ tw2, const float* __restrict__ tb2,
    float* __restrict__ part, float* __restrict__ temb) {
    const int tid = threadIdx.x;
    __shared__ float As[32][68];
    __shared__ float Bs[32][68];
    // fused time embedding (blocks z=0, by<2)
    if (blockIdx.z == 0 && blockIdx.y < 2) {
        int b = blockIdx.y * 4 + blockIdx.x;
        float* hid = &As[0][0];
        float tf = (float)t[b];
        hid[tid] = gelu_f(tf * tw1[tid] + tb1[tid]);
        __syncthreads();
        float acc = tb2[tid];
        for (int k = 0; k < 256; ++k) acc = fmaf(hid[k], tw2[k * 256 + tid], acc);
        temb[b * 256 + tid] = acc;
        __syncthreads();
    }
    const int n0 = blockIdx.x * 64, m0 = blockIdx.y * 64;
    const int kbase = blockIdx.z * 128;
    float* Cz = part + (size_t)blockIdx.z * 524288;
    const int tx = tid & 15, ty = tid >> 4;
    const int srow = tid >> 3, sk4 = tid & 7;
    // gather addressing: m -> base into x; k -> (c,p,q) offset
    int mA = m0 + srow, mB = mA + 32;
    int bA = mA >> 8, lA = mA & 255;
    int bB = mB >> 8, lB = mB & 255;
    size_t baseA = (((size_t)(bA * 2) * 256 + (lA >> 4) * 16) * 256) + (lA & 15) * 16;
    size_t baseB = (((size_t)(bB * 2) * 256 + (lB >> 4) * 16) * 256) + (lB & 15) * 16;
    const float* Bp0 = pw + (size_t)(n0 + srow) * 512 + kbase + sk4 * 4;
    const float* Bp1 = Bp0 + (size_t)32 * 512;
    int k1 = kbase + sk4 * 4;
    float4 pa0 = *(const float4*)&x[baseA + (size_t)(k1 >> 8) * 65536 + ((k1 >> 4) & 15) * 256 + (k1 & 15)];
    float4 pa1 = *(const float4*)&x[baseB + (size_t)(k1 >> 8) * 65536 + ((k1 >> 4) & 15) * 256 + (k1 & 15)];
    float4 pb0 = *(const float4*)Bp0, pb1 = *(const float4*)Bp1;
    float acc[4][4] = {};
    for (int tt = 0;; ++tt) {
        As[sk4 * 4 + 0][srow] = pa0.x;  As[sk4 * 4 + 1][srow] = pa0.y;
        As[sk4 * 4 + 2][srow] = pa0.z;  As[sk4 * 4 + 3][srow] = pa0.w;
        As[sk4 * 4 + 0][srow + 32] = pa1.x;  As[sk4 * 4 + 1][srow + 32] = pa1.y;
        As[sk4 * 4 + 2][srow + 32] = pa1.z;  As[sk4 * 4 + 3][srow + 32] = pa1.w;
        Bs[sk4 * 4 + 0][srow] = pb0.x;  Bs[sk4 * 4 + 1][srow] = pb0.y;
        Bs[sk4 * 4 + 2][srow] = pb0.z;  Bs[sk4 * 4 + 3][srow] = pb0.w;
        Bs[sk4 * 4 + 0][srow + 32] = pb1.x;  Bs[sk4 * 4 + 1][srow + 32] = pb1.y;
        Bs[sk4 * 4 + 2][srow + 32] = pb1.z;  Bs[sk4 * 4 + 3][srow + 32] = pb1.w;
        __syncthreads();
        if (tt + 1 < 4) {
            int k2 = kbase + (tt + 1) * 32 + sk4 * 4;
            size_t ko = (size_t)(k2 >> 8) * 65536 + ((k2 >> 4) & 15) * 256 + (k2 & 15);
            pa0 = *(const float4*)&x[baseA + ko];
            pa1 = *(const float4*)&x[baseB + ko];
            pb0 = *(const float4*)(Bp0 + (tt + 1) * 32);
            pb1 = *(const float4*)(Bp1 + (tt + 1) * 32);
        }
#pragma unroll
        for (int kk = 0; kk < 32; ++kk) {
            float4 av = *(const float4*)&As[kk][ty * 4];
            float4 bv = *(const float4*)&Bs[kk][tx * 4];
            float a[4] = {av.x, av.y, av.z, av.w};
            float b[4] = {bv.x, bv.y, bv.z, bv.w};
#pragma unroll
            for (int i = 0; i < 4; ++i)
#pragma unroll
                for (int j = 0; j < 4; ++j) acc[i][j] = fmaf(a[i], b[j], acc[i][j]);
        }
        if (tt + 1 >= 4) break;
        __syncthreads();
    }
#pragma unroll
    for (int i = 0; i < 4; ++i) {
        int m = m0 + ty * 4 + i;
        *(float4*)&Cz[(size_t)m * 256 + n0 + tx * 4] =
            make_float4(acc[i][0], acc[i][1], acc[i][2], acc[i][3]);
    }
}

// ============ combine patch partials + bias + pos + temb -> H ============
__global__ __launch_bounds__(256) void combine_patch(
    const float* __restrict__ part, const float* __restrict__ pb,
    const float* __restrict__ pos, const float* __restrict__ temb,
    float* __restrict__ h) {
    int m = blockIdx.x, e = threadIdx.x;
    size_t o = (size_t)m * 256 + e;
    h[o] = ((part[o] + part[524288 + o]) + (part[1048576 + o] + part[1572864 + o]))
         + pb[e] + pos[(m & 255) * 256 + e] + temb[(m >> 8) * 256 + e];
}

// ============ in_proj GEMM with fused per-row LayerNorm of A ============
// XZ[m,n] = sum_k LN(H)[m,k] * ipw[n,k]. grid (16, 32). K=256, N=1024.
__global__ __launch_bounds__(256) void in_proj_ln(
    const float* __restrict__ Hm, const float* __restrict__ Bw,
    const float* __restrict__ g, const float* __restrict__ bt,
    float* __restrict__ C) {
    const int tid = threadIdx.x;
    const int n0 = blockIdx.x * 64, m0 = blockIdx.y * 64;
    __shared__ float As[32][68];
    __shared__ float Bs[32][68];
    __shared__ float gS[256], bS[256];
    __shared__ float meanS[64], rstdS[64];
    __shared__ float sums[64][4];
    gS[tid] = g[tid];
    bS[tid] = bt[tid];
    // LN stats (two-pass) for rows m0..m0+63
    {
        int r = tid >> 2, seg = (tid & 3) * 64;
        const float* hr = Hm + (size_t)(m0 + r) * 256 + seg;
        float s = 0.0f;
#pragma unroll
        for (int k = 0; k < 64; k += 4) {
            float4 v = *(const float4*)&hr[k];
            s += (v.x + v.y) + (v.z + v.w);
        }
        sums[r][tid & 3] = s;
        __syncthreads();
        if (tid < 64)
            meanS[tid] = (sums[tid][0] + sums[tid][1] + sums[tid][2] + sums[tid][3]) * (1.0f / 256.0f);
        __syncthreads();
        float mn = meanS[r];
        s = 0.0f;
#pragma unroll
        for (int k = 0; k < 64; k += 4) {
            float4 v = *(const float4*)&hr[k];
            float d0 = v.x - mn, d1 = v.y - mn, d2 = v.z - mn, d3 = v.w - mn;
            s += (d0 * d0 + d1 * d1) + (d2 * d2 + d3 * d3);
        }
        sums[r][tid & 3] = s;
        __syncthreads();
        if (tid < 64)
            rstdS[tid] = rsqrtf((sums[tid][0] + sums[tid][1] + sums[tid][2] + sums[tid][3]) * (1.0f / 256.0f) + 1e-5f);
        __syncthreads();
    }
    const int tx = tid & 15, ty = tid >> 4;
    const int srow = tid >> 3, sk4 = tid & 7;
    const float* Ap0 = Hm + (size_t)(m0 + srow) * 256 + sk4 * 4;
    const float* Ap1 = Ap0 + (size_t)32 * 256;
    const float* Bp0 = Bw + (size_t)(n0 + srow) * 256 + sk4 * 4;
    const float* Bp1 = Bp0 + (size_t)32 * 256;
    float4 pa0 = *(const float4*)Ap0, pa1 = *(const float4*)Ap1;
    float4 pb0 = *(const float4*)Bp0, pb1 = *(const float4*)Bp1;
    float mn0 = meanS[srow], rs0 = rstdS[srow];
    float mn1 = meanS[srow + 32], rs1 = rstdS[srow + 32];
    float acc[4][4] = {};
    for (int tt = 0;; ++tt) {
        int kb = tt * 32 + sk4 * 4;
        float4 gv = *(const float4*)&gS[kb];
        float4 bv4 = *(const float4*)&bS[kb];
        As[sk4 * 4 + 0][srow] = (pa0.x - mn0) * rs0 * gv.x + bv4.x;
        As[sk4 * 4 + 1][srow] = (pa0.y - mn0) * rs0 * gv.y + bv4.y;
        As[sk4 * 4 + 2][srow] = (pa0.z - mn0) * rs0 * gv.z + bv4.z;
        As[sk4 * 4 + 3][srow] = (pa0.w - mn0) * rs0 * gv.w + bv4.w;
        As[sk4 * 4 + 0][srow + 32] = (pa1.x - mn1) * rs1 * gv.x + bv4.x;
        As[sk4 * 4 + 1][srow + 32] = (pa1.y - mn1) * rs1 * gv.y + bv4.y;
        As[sk4 * 4 + 2][srow + 32] = (pa1.z - mn1) * rs1 * gv.z + bv4.z;
        As[sk4 * 4 + 3][srow + 32] = (pa1.w - mn1) * rs1 * gv.w + bv4.w;
        Bs[sk4 * 4 + 0][srow] = pb0.x;  Bs[sk4 * 4 + 1][srow] = pb0.y;
        Bs[sk4 * 4 + 2][srow] = pb0.z;  Bs[sk4 * 4 + 3][srow] = pb0.w;
        Bs[sk4 * 4 + 0][srow + 32] = pb1.x;  Bs[sk4 * 4 + 1][srow + 32] = pb1.y;
        Bs[sk4 * 4 + 2][srow + 32] = pb1.z;  Bs[sk4 * 4 + 3][srow + 32] = pb1.w;
        __syncthreads();
        if (tt + 1 < 8) {
            int off = (tt + 1) * 32;
            pa0 = *(const float4*)(Ap0 + off);
            pa1 = *(const float4*)(Ap1 + off);
            pb0 = *(const float4*)(Bp0 + off);
            pb1 = *(const float4*)(Bp1 + off);
        }
#pragma unroll
        for (int kk = 0; kk < 32; ++kk) {
            float4 av = *(const float4*)&As[kk][ty * 4];
            float4 bv = *(const float4*)&Bs[kk][tx * 4];
            float a[4] = {av.x, av.y, av.z, av.w};
            float b[4] = {bv.x, bv.y, bv.z, bv.w};
#pragma unroll
            for (int i = 0; i < 4; ++i)
#pragma unroll
                for (int j = 0; j < 4; ++j) acc[i][j] = fmaf(a[i], b[j], acc[i][j]);
        }
        if (tt + 1 >= 8) break;
        __syncthreads();
    }
#pragma unroll
    for (int i = 0; i < 4; ++i) {
        int m = m0 + ty * 4 + i;
        *(float4*)&C[(size_t)m * 1024 + n0 + tx * 4] =
            make_float4(acc[i][0], acc[i][1], acc[i][2], acc[i][3]);
    }
}

// ============ scan phase 1: in-block conv+silu+dbc, local chunk scan ============
// grid (NC, NB, 2), 256 thr.
__global__ __launch_bounds__(256) void scan_phase1(
    const float* __restrict__ xz, const float* __restrict__ xpw,
    const float* __restrict__ cw, const float* __restrict__ cb,
    const float* __restrict__ dtw, const float* __restrict__ dtb,
    const float* __restrict__ alog,
    float* __restrict__ dbc_g, float* __restrict__ hpart, float* __restrict__ pprod) {
    const int c = blockIdx.x, b = blockIdx.y, z = blockIdx.z;
    const int tid = threadIdx.x;
    const int d = z * 256 + tid;
    __shared__ float xzS[11][512];
    __shared__ float uS[8][512];
    __shared__ float partS[4][8][48];
    __shared__ float dbcS[8][48];
    // stage xz u-half rows (c*8-3 .. c*8+7), zero-pad below 0
    for (int idx = tid; idx < 11 * 128; idx += 256) {
        int r = idx >> 7, c4 = (idx & 127) << 2;
        int gl = c * 8 - 3 + r;
        float4 v = make_float4(0.f, 0.f, 0.f, 0.f);
        if (gl >= 0) v = *(const float4*)&xz[((size_t)(b * 256 + gl)) * 1024 + c4];
        *(float4*)&xzS[r][c4] = v;
    }
    __syncthreads();
    // u = silu(conv) for all 512 channels x 8 tokens
    for (int i = tid; i < 4096; i += 256) {
        int r = i >> 9, dd = i & 511;
        float4 w4 = *(const float4*)&cw[dd * 4];
        float a = cb[dd];
        a = fmaf(xzS[r + 0][dd], w4.x, a);
        a = fmaf(xzS[r + 1][dd], w4.y, a);
        a = fmaf(xzS[r + 2][dd], w4.z, a);
        a = fmaf(xzS[r + 3][dd], w4.w, a);
        uS[r][dd] = silu_f(a);
    }
    __syncthreads();
    // dbc[r][col] = sum_k u[r][k]*xpw[col][k], k split in 4 quarters over 192 threads
    if (tid < 192) {
        int col = tid % 48, kq = tid / 48;
        const float* wp = xpw + (size_t)col * 512 + kq * 128;
        float accq[8] = {};
        for (int k = 0; k < 128; k += 4) {
            float4 w4 = *(const float4*)&wp[k];
            int kk = kq * 128 + k;
#pragma unroll
            for (int r = 0; r < 8; ++r) {
                float4 u4 = *(const float4*)&uS[r][kk];
                accq[r] = fmaf(u4.x, w4.x, accq[r]);
                accq[r] = fmaf(u4.y, w4.y, accq[r]);
                accq[r] = fmaf(u4.z, w4.z, accq[r]);
                accq[r] = fmaf(u4.w, w4.w, accq[r]);
            }
        }
#pragma unroll
        for (int r = 0; r < 8; ++r) partS[kq][r][col] = accq[r];
    }
    __syncthreads();
    if (tid < 384) {
        int r = tid / 48, col = tid % 48;
        float v = (partS[0][r][col] + partS[1][r][col]) + (partS[2][r][col] + partS[3][r][col]);
        dbcS[r][col] = v;
        if (z == 0) dbc_g[((size_t)(b * 256 + c * 8 + r)) * 48 + col] = v;
    }
    // per-channel params
    float wv[16], Av[16];
#pragma unroll
    for (int s4 = 0; s4 < 16; s4 += 4) {
        float4 t1 = *(const float4*)(dtw + d * 16 + s4);
        wv[s4] = t1.x; wv[s4 + 1] = t1.y; wv[s4 + 2] = t1.z; wv[s4 + 3] = t1.w;
        float4 t2 = *(const float4*)(alog + d * 16 + s4);
        Av[s4] = -expf(t2.x); Av[s4 + 1] = -expf(t2.y);
        Av[s4 + 2] = -expf(t2.z); Av[s4 + 3] = -expf(t2.w);
    }
    float bv = dtb[d];
    float h[16] = {}, P[16];
#pragma unroll
    for (int s = 0; s < 16; ++s) P[s] = 1.0f;
    __syncthreads();
    for (int r = 0; r < CL; ++r) {
        float uv = uS[r][d];
        float pre = bv;
#pragma unroll
        for (int j = 0; j < 16; ++j) pre = fmaf(dbcS[r][j], wv[j], pre);
        float dt = softplus_f(pre);
        float du = dt * uv;
#pragma unroll
        for (int s = 0; s < 16; ++s) {
            float dA = expf(dt * Av[s]);
            h[s] = fmaf(dA, h[s], du * dbcS[r][16 + s]);
            P[s] *= dA;
        }
    }
    size_t base = ((size_t)((b * NC + c) * DI) + d) * 16;
#pragma unroll
    for (int s = 0; s < 16; ++s) { hpart[base + s] = h[s]; pprod[base + s] = P[s]; }
}

// ============ scan phase 3: prefix fold + replay, y*silu(z) ============
__global__ __launch_bounds__(256) void scan_phase3(
    const float* __restrict__ xz, const float* __restrict__ dbc_g,
    const float* __restrict__ cw, const float* __restrict__ cb,
    const float* __restrict__ dtw, const float* __restrict__ dtb,
    const float* __restrict__ alog, const float* __restrict__ Dpv,
    const float* __restrict__ hpart, const float* __restrict__ pprod,
    float* __restrict__ yz) {
    const int c = blockIdx.x, b = blockIdx.y, z = blockIdx.z;
    const int tid = threadIdx.x;
    const int d = z * 256 + tid;
    __shared__ float xzS[11][256];
    __shared__ float uS[8][256];
    __shared__ float dbcS[8][48];
    for (int idx = tid; idx < 11 * 64; idx += 256) {
        int r = idx >> 6, c4 = (idx & 63) << 2;
        int gl = c * 8 - 3 + r;
        float4 v = make_float4(0.f, 0.f, 0.f, 0.f);
        if (gl >= 0) v = *(const float4*)&xz[((size_t)(b * 256 + gl)) * 1024 + z * 256 + c4];
        *(float4*)&xzS[r][c4] = v;
    }
    __syncthreads();
    for (int i = tid; i < 2048; i += 256) {
        int r = i >> 8, dd = i & 255;
        float4 w4 = *(const float4*)&cw[(z * 256 + dd) * 4];
        float a = cb[z * 256 + dd];
        a = fmaf(xzS[r + 0][dd], w4.x, a);
        a = fmaf(xzS[r + 1][dd], w4.y, a);
        a = fmaf(xzS[r + 2][dd], w4.z, a);
        a = fmaf(xzS[r + 3][dd], w4.w, a);
        uS[r][dd] = silu_f(a);
    }
    if (tid < 384) {
        int r = tid / 48, col = tid % 48;
        dbcS[r][col] = dbc_g[((size_t)(b * 256 + c * 8 + r)) * 48 + col];
    }
    float wv[16], Av[16];
#pragma unroll
    for (int s4 = 0; s4 < 16; s4 += 4) {
        float4 t1 = *(const float4*)(dtw + d * 16 + s4);
        wv[s4] = t1.x; wv[s4 + 1] = t1.y; wv[s4 + 2] = t1.z; wv[s4 + 3] = t1.w;
        float4 t2 = *(const float4*)(alog + d * 16 + s4);
        Av[s4] = -expf(t2.x); Av[s4 + 1] = -expf(t2.y);
        Av[s4 + 2] = -expf(t2.z); Av[s4 + 3] = -expf(t2.w);
    }
    float bv = dtb[d];
    float Dv = Dpv[d];
    // chunk-prefix carry from partials
    float h[16] = {};
    for (int cc = 0; cc < c; ++cc) {
        size_t a = ((size_t)((b * NC + cc) * DI) + d) * 16;
#pragma unroll
        for (int s4 = 0; s4 < 16; s4 += 4) {
            float4 hp = *(const float4*)&hpart[a + s4];
            float4 pp = *(const float4*)&pprod[a + s4];
            h[s4 + 0] = fmaf(pp.x, h[s4 + 0], hp.x);
            h[s4 + 1] = fmaf(pp.y, h[s4 + 1], hp.y);
            h[s4 + 2] = fmaf(pp.z, h[s4 + 2], hp.z);
            h[s4 + 3] = fmaf(pp.w, h[s4 + 3], hp.w);
        }
    }
    const float* zrow = xz + ((size_t)(b * 256 + c * 8)) * 1024 + 512 + d;
    float* yrow = yz + ((size_t)(b * 256 + c * 8)) * 512 + d;
    __syncthreads();
    for (int r = 0; r < CL; ++r) {
        float uv = uS[r][tid];
        float pre = bv;
#pragma unroll
        for (int j = 0; j < 16; ++j) pre = fmaf(dbcS[r][j], wv[j], pre);
        float dt = softplus_f(pre);
        float du = dt * uv;
        float y = uv * Dv;
#pragma unroll
        for (int s = 0; s < 16; ++s) {
            float dA = expf(dt * Av[s]);
            h[s] = fmaf(dA, h[s], du * dbcS[r][16 + s]);
            y = fmaf(h[s], dbcS[r][32 + s], y);
        }
        float zv = zrow[r * 1024];
        yrow[r * 512] = y * silu_f(zv);
    }
}

// ============ out_proj GEMM, atomic accumulate into H (residual) ============
// grid (4, 32, 4). K=512 split 4 (128/slice). A=YZ (2048x512), B=opw (256x512).
__global__ __launch_bounds__(256) void outproj_gemm(
    const float* __restrict__ A, const float* __restrict__ Bw,
    float* __restrict__ Hout) {
    const int tid = threadIdx.x;
    const int n0 = blockIdx.x * 64, m0 = blockIdx.y * 64;
    const int kbase = blockIdx.z * 128;
    __shared__ float As[32][68];
    __shared__ float Bs[32][68];
    const int tx = tid & 15, ty = tid >> 4;
    const int srow = tid >> 3, sk4 = tid & 7;
    const float* Ap0 = A + (size_t)(m0 + srow) * 512 + kbase + sk4 * 4;
    const float* Ap1 = Ap0 + (size_t)32 * 512;
    const float* Bp0 = Bw + (size_t)(n0 + srow) * 512 + kbase + sk4 * 4;
    const float* Bp1 = Bp0 + (size_t)32 * 512;
    float4 pa0 = *(const float4*)Ap0, pa1 = *(const float4*)Ap1;
    float4 pb0 = *(const float4*)Bp0, pb1 = *(const float4*)Bp1;
    float acc[4][4] = {};
    for (int tt = 0;; ++tt) {
        As[sk4 * 4 + 0][srow] = pa0.x;  As[sk4 * 4 + 1][srow] = pa0.y;
        As[sk4 * 4 + 2][srow] = pa0.z;  As[sk4 * 4 + 3][srow] = pa0.w;
        As[sk4 * 4 + 0][srow + 32] = pa1.x;  As[sk4 * 4 + 1][srow + 32] = pa1.y;
        As[sk4 * 4 + 2][srow + 32] = pa1.z;  As[sk4 * 4 + 3][srow + 32] = pa1.w;
        Bs[sk4 * 4 + 0][srow] = pb0.x;  Bs[sk4 * 4 + 1][srow] = pb0.y;
        Bs[sk4 * 4 + 2][srow] = pb0.z;  Bs[sk4 * 4 + 3][srow] = pb0.w;
        Bs[sk4 * 4 + 0][srow + 32] = pb1.x;  Bs[sk4 * 4 + 1][srow + 32] = pb1.y;
        Bs[sk4 * 4 + 2][srow + 32] = pb1.z;  Bs[sk4 * 4 + 3][srow + 32] = pb1.w;
        __syncthreads();
        if (tt + 1 < 4) {
            int off = (tt + 1) * 32;
            pa0 = *(const float4*)(Ap0 + off);
            pa1 = *(const float4*)(Ap1 + off);
            pb0 = *(const float4*)(Bp0 + off);
            pb1 = *(const float4*)(Bp1 + off);
        }
#pragma unroll
        for (int kk = 0; kk < 32; ++kk) {
            float4 av = *(const float4*)&As[kk][ty * 4];
            float4 bv = *(const float4*)&Bs[kk][tx * 4];
            float a[4] = {av.x, av.y, av.z, av.w};
            float b[4] = {bv.x, bv.y, bv.z, bv.w};
#pragma unroll
            for (int i = 0; i < 4; ++i)
#pragma unroll
                for (int j = 0; j < 4; ++j) acc[i][j] = fmaf(a[i], b[j], acc[i][j]);
        }
        if (tt + 1 >= 4) break;
        __syncthreads();
    }
#pragma unroll
    for (int i = 0; i < 4; ++i) {
        int m = m0 + ty * 4 + i;
#pragma unroll
        for (int j = 0; j < 4; ++j)
            atomicAdd(&Hout[(size_t)m * 256 + n0 + tx * 4 + j], acc[i][j]);
    }
}

// ============ decoder convT 2x2 s2 as GEMM + bias + gelu (dec1, dec2) ============
template <int BM, bool AROW>
__global__ __launch_bounds__(256) void convt_gemm(
    const float* __restrict__ A, const float* __restrict__ Wt, const float* __restrict__ bias,
    float* __restrict__ out, int K, int N, int HW, int Wdim, int O) {
    constexpr int TM = BM / 16;
    const int tid = threadIdx.x;
    const int n0 = blockIdx.x * 64;
    const int m0 = blockIdx.y * BM;
    __shared__ float As[32][BM + 4];
    __shared__ float Bs[32][68];
    const int tx = tid & 15, ty = tid >> 4;
    float acc[TM][4] = {};
    const int T = K >> 5;
    float4 pa0, pa1;
    float pra[BM / 8];
    float prb[8];
    const int srow = tid >> 3, sk4 = tid & 7;
    const float* Ap0 = nullptr; const float* Ap1 = nullptr; const float* Ab = nullptr;
    if constexpr (AROW) {
        Ap0 = A + (size_t)(m0 + srow) * K + sk4 * 4;
        Ap1 = Ap0 + (size_t)32 * K;
        pa0 = *(const float4*)Ap0;
        if constexpr (BM == 64) pa1 = *(const float4*)Ap1;
    } else {
        int bb = m0 / HW, hw0 = m0 % HW;
        Ab = A + ((size_t)bb * K) * HW + hw0;
#pragma unroll
        for (int f = 0; f < BM / 8; ++f)
            pra[f] = Ab[(size_t)((tid >> 6) + 4 * f) * HW + (tid & 63)];
    }
#pragma unroll
    for (int f = 0; f < 8; ++f)
        prb[f] = Wt[(size_t)((tid >> 6) + 4 * f) * N + n0 + (tid & 63)];
    for (int t = 0;; ++t) {
        if constexpr (AROW) {
            As[sk4 * 4 + 0][srow] = pa0.x;  As[sk4 * 4 + 1][srow] = pa0.y;
            As[sk4 * 4 + 2][srow] = pa0.z;  As[sk4 * 4 + 3][srow] = pa0.w;
            if constexpr (BM == 64) {
                As[sk4 * 4 + 0][srow + 32] = pa1.x;  As[sk4 * 4 + 1][srow + 32] = pa1.y;
                As[sk4 * 4 + 2][srow + 32] = pa1.z;  As[sk4 * 4 + 3][srow + 32] = pa1.w;
            }
        } else {
#pragma unroll
            for (int f = 0; f < BM / 8; ++f)
                As[(tid >> 6) + 4 * f][tid & 63] = pra[f];
        }
#pragma unroll
        for (int f = 0; f < 8; ++f)
            Bs[(tid >> 6) + 4 * f][tid & 63] = prb[f];
        __syncthreads();
        if (t + 1 < T) {
            int off = (t + 1) * 32;
            if constexpr (AROW) {
                pa0 = *(const float4*)(Ap0 + off);
                if constexpr (BM == 64) pa1 = *(const float4*)(Ap1 + off);
            } else {
#pragma unroll
                for (int f = 0; f < BM / 8; ++f)
                    pra[f] = Ab[(size_t)(off + (tid >> 6) + 4 * f) * HW + (tid & 63)];
            }
#pragma unroll
            for (int f = 0; f < 8; ++f)
                prb[f] = Wt[(size_t)(off + (tid >> 6) + 4 * f) * N + n0 + (tid & 63)];
        }
#pragma unroll
        for (int kk = 0; kk < 32; ++kk) {
            float a[TM];
#pragma unroll
            for (int i = 0; i < TM; ++i) a[i] = As[kk][ty * TM + i];
            float4 bv = *(const float4*)&Bs[kk][tx * 4];
            float b[4] = {bv.x, bv.y, bv.z, bv.w};
#pragma unroll
            for (int i = 0; i < TM; ++i)
#pragma unroll
                for (int j = 0; j < 4; ++j) acc[i][j] = fmaf(a[i], b[j], acc[i][j]);
        }
        if (t + 1 >= T) break;
        __syncthreads();
    }
    int Hdim = HW / Wdim;
#pragma unroll
    for (int i = 0; i < TM; ++i) {
        int m = m0 + ty * TM + i;
        int b = m / HW, hw = m % HW;
        int hh = hw / Wdim, ww = hw % Wdim;
#pragma unroll
        for (int j = 0; j < 4; ++j) {
            int n = n0 + tx * 4 + j;
            int o = n >> 2, p = (n >> 1) & 1, q = n & 1;
            out[(((size_t)(b * O + o)) * (2 * Hdim) + 2 * hh + p) * (size_t)(2 * Wdim) + 2 * ww + q] =
                gelu_f(acc[i][j] + bias[o]);
        }
    }
}

// ============ dec3 (K=64 -> 32ch,2x2) fused with dec4 (32ch -> 1ch,2x2) ============
// grid 1024 blocks, 256 thr. A = D2 (8,64,64,64) k-major; BM=32 pixels, BN=128 (full).
__global__ __launch_bounds__(256) void dec34_kernel(
    const float* __restrict__ A, const float* __restrict__ W3, const float* __restrict__ b3,
    const float* __restrict__ w4, const float* __restrict__ b4,
    float* __restrict__ out) {
    const int tid = threadIdx.x;
    const int m0 = blockIdx.x * 32;
    __shared__ float As[32][36];
    __shared__ float Bs[32][132];
    __shared__ float d3S[32][4][33];
    __shared__ float w4S[128];
    if (tid < 128) w4S[tid] = w4[tid];
    const int tx = tid & 15, ty = tid >> 4;
    float acc[2][8] = {};
    int bb = m0 >> 12, hw0 = m0 & 4095;
    const float* Ab = A + ((size_t)bb * 64) * 4096 + hw0;
    for (int t = 0; t < 2; ++t) {
        int k0 = t * 32;
        for (int idx = tid; idx < 1024; idx += 256) {
            int kk = idx >> 5, mm = idx & 31;
            As[kk][mm] = Ab[(size_t)(k0 + kk) * 4096 + mm];
        }
        for (int idx = tid; idx < 4096; idx += 256) {
            int kk = idx >> 7, nn = idx & 127;
            Bs[kk][nn] = W3[(size_t)(k0 + kk) * 128 + nn];
        }
        __syncthreads();
#pragma unroll
        for (int kk = 0; kk < 32; ++kk) {
            float a0 = As[kk][ty * 2 + 0];
            float a1 = As[kk][ty * 2 + 1];
            float4 b0 = *(const float4*)&Bs[kk][tx * 8];
            float4 b1 = *(const float4*)&Bs[kk][tx * 8 + 4];
            float bb8[8] = {b0.x, b0.y, b0.z, b0.w, b1.x, b1.y, b1.z, b1.w};
#pragma unroll
            for (int j = 0; j < 8; ++j) {
                acc[0][j] = fmaf(a0, bb8[j], acc[0][j]);
                acc[1][j] = fmaf(a1, bb8[j], acc[1][j]);
            }
        }
        __syncthreads();
    }
    // d3 tile (gelu) into LDS: d3S[pixel][pq][channel]
#pragma unroll
    for (int i = 0; i < 2; ++i) {
        int m_loc = ty * 2 + i;
#pragma unroll
        for (int j = 0; j < 8; ++j) {
            int n = tx * 8 + j;
            int o = n >> 2, pq = n & 3;
            d3S[m_loc][pq][o] = gelu_f(acc[i][j] + b3[o]);
        }
    }
    __syncthreads();
    // dec4: each d3 pixel -> 4 final outputs
    float bias4 = b4[0];
#pragma unroll
    for (int it = 0; it < 2; ++it) {
        int oi = tid + 256 * it;
        int m_loc = oi >> 4, rem = oi & 15, pq = rem >> 2, pq2 = rem & 3;
        float s = bias4;
#pragma unroll
        for (int cch = 0; cch < 32; ++cch)
            s = fmaf(d3S[m_loc][pq][cch], w4S[cch * 4 + pq2], s);
        int m_glob = m0 + m_loc;
        int b = m_glob >> 12, hw = m_glob & 4095, hh = hw >> 6, ww = hw & 63;
        int H128 = 2 * hh + (pq >> 1), W128 = 2 * ww + (pq & 1);
        int row = 2 * H128 + (pq2 >> 1), col = 2 * W128 + (pq2 & 1);
        out[(size_t)b * 65536 + (size_t)row * 256 + col] = s;
    }
}

// ---------------- workspace layout (floats) ----------------
#define H_OFF     ((size_t)0)          // 524288
#define TEMB_OFF  ((size_t)524288)     // 2048
#define PART_OFF  ((size_t)526336)     // 4 x 524288 = 2097152
#define XZ_OFF    ((size_t)2623488)    // 2097152
#define YZ_OFF    ((size_t)4720640)    // 1048576
#define DBC_OFF   ((size_t)5769216)    // 98304
#define HPART_OFF ((size_t)5867520)    // 2097152
#define PPROD_OFF ((size_t)7964672)    // 2097152  (end 10061824)

extern "C" void kernel_launch(void* const* d_in, const int* in_sizes, int n_in,
                              void* d_out, int out_size, void* d_ws, size_t ws_size,
                              hipStream_t stream) {
    (void)in_sizes; (void)n_in; (void)out_size; (void)ws_size;
    const float* x    = (const float*)d_in[0];
    const int*   t    = (const int*)d_in[1];
    const float* tw1  = (const float*)d_in[2];
    const float* tb1  = (const float*)d_in[3];
    const float* tw2  = (const float*)d_in[4];
    const float* tb2  = (const float*)d_in[5];
    const float* pw   = (const float*)d_in[6];
    const float* pb   = (const float*)d_in[7];
    const float* pos  = (const float*)d_in[8];
    const float* lng  = (const float*)d_in[9];
    const float* lnb  = (const float*)d_in[10];
    const float* ipw  = (const float*)d_in[11];
    const float* cw   = (const float*)d_in[12];
    const float* cb   = (const float*)d_in[13];
    const float* xpw  = (const float*)d_in[14];
    const float* dtw  = (const float*)d_in[15];
    const float* dtb  = (const float*)d_in[16];
    const float* alog = (const float*)d_in[17];
    const float* Dp   = (const float*)d_in[18];
    const float* opw  = (const float*)d_in[19];
    const float* dw1  = (const float*)d_in[20];
    const float* db1  = (const float*)d_in[21];
    const float* dw2  = (const float*)d_in[22];
    const float* db2  = (const float*)d_in[23];
    const float* dw3  = (const float*)d_in[24];
    const float* db3  = (const float*)d_in[25];
    const float* dw4  = (const float*)d_in[26];
    const float* db4  = (const float*)d_in[27];

    float* ws    = (float*)d_ws;
    float* H     = ws + H_OFF;
    float* TEMB  = ws + TEMB_OFF;
    float* PART  = ws + PART_OFF;
    float* XZ    = ws + XZ_OFF;
    float* YZ    = ws + YZ_OFF;
    float* DBC   = ws + DBC_OFF;
    float* HPART = ws + HPART_OFF;
    float* PPROD = ws + PPROD_OFF;
    float* D1    = YZ;      // 1048576 floats, lifetime disjoint
    float* D2    = HPART;   // 2097152 floats, lifetime disjoint

    patch_gemm<<<dim3(4, 32, 4), 256, 0, stream>>>(x, pw, t, tw1, tb1, tw2, tb2, PART, TEMB);
    combine_patch<<<2048, 256, 0, stream>>>(PART, pb, pos, TEMB, H);

    for (int i = 0; i < 8; ++i) {
        in_proj_ln<<<dim3(16, 32), 256, 0, stream>>>(
            H, ipw + (size_t)i * 262144, lng + (size_t)i * 256, lnb + (size_t)i * 256, XZ);
        scan_phase1<<<dim3(NC, NB, 2), 256, 0, stream>>>(
            XZ, xpw + (size_t)i * 24576, cw + (size_t)i * 2048, cb + (size_t)i * 512,
            dtw + (size_t)i * 8192, dtb + (size_t)i * 512, alog + (size_t)i * 8192,
            DBC, HPART, PPROD);
        scan_phase3<<<dim3(NC, NB, 2), 256, 0, stream>>>(
            XZ, DBC, cw + (size_t)i * 2048, cb + (size_t)i * 512,
            dtw + (size_t)i * 8192, dtb + (size_t)i * 512, alog + (size_t)i * 8192,
            Dp + (size_t)i * 512, HPART, PPROD, YZ);
        outproj_gemm<<<dim3(4, 32, 4), 256, 0, stream>>>(YZ, opw + (size_t)i * 131072, H);
    }

    // decoder
    convt_gemm<32, true><<<dim3(8, 64), 256, 0, stream>>>(H, dw1, db1, D1, 256, 512, 256, 16, 128);
    convt_gemm<64, false><<<dim3(4, 128), 256, 0, stream>>>(D1, dw2, db2, D2, 128, 256, 1024, 32, 64);
    dec34_kernel<<<1024, 256, 0, stream>>>(D2, dw3, db3, dw4, db4, (float*)d_out);
}

// Round 9
// 1085.869 us; speedup vs baseline: 3.9977x; 1.1605x over previous
//
#include <hip/hip_runtime.h>
#include <math.h>

// ---------------- model dims ----------------
#define NB    8
#define E     256
#define LTOK  256
#define DI    512
#define DS    16
#define DTR   16
#define NC    32     // scan chunks
#define CL    8      // chunk length

__device__ __forceinline__ float gelu_f(float x) {
    return 0.5f * x * (1.0f + erff(x * 0.70710678118654752440f));
}
__device__ __forceinline__ float silu_f(float x) {
    return x / (1.0f + expf(-x));
}
__device__ __forceinline__ float softplus_f(float x) {
    return fmaxf(x, 0.0f) + log1pf(expf(-fabsf(x)));
}

// ============ patch-embed GEMM (gather fused) + time-emb on 8 blocks ============
// grid (4, 32, 4), 256 thr. C partials: PART[z][2048][256]. K=512 split 4.
__global__ __launch_bounds__(256) void patch_gemm(
    const float* __restrict__ x, const float* __restrict__ pw,
    const int* __restrict__ t,
    const float* __restrict__ tw1, const float* __restrict__ tb1,
    const float* __restrict__ tw2, const float* __restrict__ tb2,
    float* __restrict__ part, float* __restrict__ temb) {
    const int tid = threadIdx.x;
    __shared__ float As[32][68];
    __shared__ float Bs[32][68];
    // fused time embedding (blocks z=0, by<2)
    if (blockIdx.z == 0 && blockIdx.y < 2) {
        int b = blockIdx.y * 4 + blockIdx.x;
        float* hid = &As[0][0];
        float tf = (float)t[b];
        hid[tid] = gelu_f(tf * tw1[tid] + tb1[tid]);
        __syncthreads();
        float acc = tb2[tid];
        for (int k = 0; k < 256; ++k) acc = fmaf(hid[k], tw2[k * 256 + tid], acc);
        temb[b * 256 + tid] = acc;
        __syncthreads();
    }
    const int n0 = blockIdx.x * 64, m0 = blockIdx.y * 64;
    const int kbase = blockIdx.z * 128;
    float* Cz = part + (size_t)blockIdx.z * 524288;
    const int tx = tid & 15, ty = tid >> 4;
    const int srow = tid >> 3, sk4 = tid & 7;
    // gather addressing: m -> base into x; k -> (c,p,q) offset
    int mA = m0 + srow, mB = mA + 32;
    int bA = mA >> 8, lA = mA & 255;
    int bB = mB >> 8, lB = mB & 255;
    size_t baseA = (((size_t)(bA * 2) * 256 + (lA >> 4) * 16) * 256) + (lA & 15) * 16;
    size_t baseB = (((size_t)(bB * 2) * 256 + (lB >> 4) * 16) * 256) + (lB & 15) * 16;
    const float* Bp0 = pw + (size_t)(n0 + srow) * 512 + kbase + sk4 * 4;
    const float* Bp1 = Bp0 + (size_t)32 * 512;
    int k1 = kbase + sk4 * 4;
    float4 pa0 = *(const float4*)&x[baseA + (size_t)(k1 >> 8) * 65536 + ((k1 >> 4) & 15) * 256 + (k1 & 15)];
    float4 pa1 = *(const float4*)&x[baseB + (size_t)(k1 >> 8) * 65536 + ((k1 >> 4) & 15) * 256 + (k1 & 15)];
    float4 pb0 = *(const float4*)Bp0, pb1 = *(const float4*)Bp1;
    float acc[4][4] = {};
    for (int tt = 0;; ++tt) {
        As[sk4 * 4 + 0][srow] = pa0.x;  As[sk4 * 4 + 1][srow] = pa0.y;
        As[sk4 * 4 + 2][srow] = pa0.z;  As[sk4 * 4 + 3][srow] = pa0.w;
        As[sk4 * 4 + 0][srow + 32] = pa1.x;  As[sk4 * 4 + 1][srow + 32] = pa1.y;
        As[sk4 * 4 + 2][srow + 32] = pa1.z;  As[sk4 * 4 + 3][srow + 32] = pa1.w;
        Bs[sk4 * 4 + 0][srow] = pb0.x;  Bs[sk4 * 4 + 1][srow] = pb0.y;
        Bs[sk4 * 4 + 2][srow] = pb0.z;  Bs[sk4 * 4 + 3][srow] = pb0.w;
        Bs[sk4 * 4 + 0][srow + 32] = pb1.x;  Bs[sk4 * 4 + 1][srow + 32] = pb1.y;
        Bs[sk4 * 4 + 2][srow + 32] = pb1.z;  Bs[sk4 * 4 + 3][srow + 32] = pb1.w;
        __syncthreads();
        if (tt + 1 < 4) {
            int k2 = kbase + (tt + 1) * 32 + sk4 * 4;
            size_t ko = (size_t)(k2 >> 8) * 65536 + ((k2 >> 4) & 15) * 256 + (k2 & 15);
            pa0 = *(const float4*)&x[baseA + ko];
            pa1 = *(const float4*)&x[baseB + ko];
            pb0 = *(const float4*)(Bp0 + (tt + 1) * 32);
            pb1 = *(const float4*)(Bp1 + (tt + 1) * 32);
        }
#pragma unroll
        for (int kk = 0; kk < 32; ++kk) {
            float4 av = *(const float4*)&As[kk][ty * 4];
            float4 bv = *(const float4*)&Bs[kk][tx * 4];
            float a[4] = {av.x, av.y, av.z, av.w};
            float b[4] = {bv.x, bv.y, bv.z, bv.w};
#pragma unroll
            for (int i = 0; i < 4; ++i)
#pragma unroll
                for (int j = 0; j < 4; ++j) acc[i][j] = fmaf(a[i], b[j], acc[i][j]);
        }
        if (tt + 1 >= 4) break;
        __syncthreads();
    }
#pragma unroll
    for (int i = 0; i < 4; ++i) {
        int m = m0 + ty * 4 + i;
        *(float4*)&Cz[(size_t)m * 256 + n0 + tx * 4] =
            make_float4(acc[i][0], acc[i][1], acc[i][2], acc[i][3]);
    }
}

// ============ combine patch partials + bias + pos + temb -> H ============
__global__ __launch_bounds__(256) void combine_patch(
    const float* __restrict__ part, const float* __restrict__ pb,
    const float* __restrict__ pos, const float* __restrict__ temb,
    float* __restrict__ h) {
    int m = blockIdx.x, e = threadIdx.x;
    size_t o = (size_t)m * 256 + e;
    h[o] = ((part[o] + part[524288 + o]) + (part[1048576 + o] + part[1572864 + o]))
         + pb[e] + pos[(m & 255) * 256 + e] + temb[(m >> 8) * 256 + e];
}

// ============ in_proj GEMM with fused per-row LayerNorm of A ============
// XZ[m,n] = sum_k LN(H)[m,k] * ipw[n,k]. grid (16, 32). K=256, N=1024.
__global__ __launch_bounds__(256) void in_proj_ln(
    const float* __restrict__ Hm, const float* __restrict__ Bw,
    const float* __restrict__ g, const float* __restrict__ bt,
    float* __restrict__ C) {
    const int tid = threadIdx.x;
    const int n0 = blockIdx.x * 64, m0 = blockIdx.y * 64;
    __shared__ float As[32][68];
    __shared__ float Bs[32][68];
    __shared__ float gS[256], bS[256];
    __shared__ float meanS[64], rstdS[64];
    __shared__ float sums[64][4];
    gS[tid] = g[tid];
    bS[tid] = bt[tid];
    // LN stats (two-pass) for rows m0..m0+63
    {
        int r = tid >> 2, seg = (tid & 3) * 64;
        const float* hr = Hm + (size_t)(m0 + r) * 256 + seg;
        float s = 0.0f;
#pragma unroll
        for (int k = 0; k < 64; k += 4) {
            float4 v = *(const float4*)&hr[k];
            s += (v.x + v.y) + (v.z + v.w);
        }
        sums[r][tid & 3] = s;
        __syncthreads();
        if (tid < 64)
            meanS[tid] = (sums[tid][0] + sums[tid][1] + sums[tid][2] + sums[tid][3]) * (1.0f / 256.0f);
        __syncthreads();
        float mn = meanS[r];
        s = 0.0f;
#pragma unroll
        for (int k = 0; k < 64; k += 4) {
            float4 v = *(const float4*)&hr[k];
            float d0 = v.x - mn, d1 = v.y - mn, d2 = v.z - mn, d3 = v.w - mn;
            s += (d0 * d0 + d1 * d1) + (d2 * d2 + d3 * d3);
        }
        sums[r][tid & 3] = s;
        __syncthreads();
        if (tid < 64)
            rstdS[tid] = rsqrtf((sums[tid][0] + sums[tid][1] + sums[tid][2] + sums[tid][3]) * (1.0f / 256.0f) + 1e-5f);
        __syncthreads();
    }
    const int tx = tid & 15, ty = tid >> 4;
    const int srow = tid >> 3, sk4 = tid & 7;
    const float* Ap0 = Hm + (size_t)(m0 + srow) * 256 + sk4 * 4;
    const float* Ap1 = Ap0 + (size_t)32 * 256;
    const float* Bp0 = Bw + (size_t)(n0 + srow) * 256 + sk4 * 4;
    const float* Bp1 = Bp0 + (size_t)32 * 256;
    float4 pa0 = *(const float4*)Ap0, pa1 = *(const float4*)Ap1;
    float4 pb0 = *(const float4*)Bp0, pb1 = *(const float4*)Bp1;
    float mn0 = meanS[srow], rs0 = rstdS[srow];
    float mn1 = meanS[srow + 32], rs1 = rstdS[srow + 32];
    float acc[4][4] = {};
    for (int tt = 0;; ++tt) {
        int kb = tt * 32 + sk4 * 4;
        float4 gv = *(const float4*)&gS[kb];
        float4 bv4 = *(const float4*)&bS[kb];
        As[sk4 * 4 + 0][srow] = (pa0.x - mn0) * rs0 * gv.x + bv4.x;
        As[sk4 * 4 + 1][srow] = (pa0.y - mn0) * rs0 * gv.y + bv4.y;
        As[sk4 * 4 + 2][srow] = (pa0.z - mn0) * rs0 * gv.z + bv4.z;
        As[sk4 * 4 + 3][srow] = (pa0.w - mn0) * rs0 * gv.w + bv4.w;
        As[sk4 * 4 + 0][srow + 32] = (pa1.x - mn1) * rs1 * gv.x + bv4.x;
        As[sk4 * 4 + 1][srow + 32] = (pa1.y - mn1) * rs1 * gv.y + bv4.y;
        As[sk4 * 4 + 2][srow + 32] = (pa1.z - mn1) * rs1 * gv.z + bv4.z;
        As[sk4 * 4 + 3][srow + 32] = (pa1.w - mn1) * rs1 * gv.w + bv4.w;
        Bs[sk4 * 4 + 0][srow] = pb0.x;  Bs[sk4 * 4 + 1][srow] = pb0.y;
        Bs[sk4 * 4 + 2][srow] = pb0.z;  Bs[sk4 * 4 + 3][srow] = pb0.w;
        Bs[sk4 * 4 + 0][srow + 32] = pb1.x;  Bs[sk4 * 4 + 1][srow + 32] = pb1.y;
        Bs[sk4 * 4 + 2][srow + 32] = pb1.z;  Bs[sk4 * 4 + 3][srow + 32] = pb1.w;
        __syncthreads();
        if (tt + 1 < 8) {
            int off = (tt + 1) * 32;
            pa0 = *(const float4*)(Ap0 + off);
            pa1 = *(const float4*)(Ap1 + off);
            pb0 = *(const float4*)(Bp0 + off);
            pb1 = *(const float4*)(Bp1 + off);
        }
#pragma unroll
        for (int kk = 0; kk < 32; ++kk) {
            float4 av = *(const float4*)&As[kk][ty * 4];
            float4 bv = *(const float4*)&Bs[kk][tx * 4];
            float a[4] = {av.x, av.y, av.z, av.w};
            float b[4] = {bv.x, bv.y, bv.z, bv.w};
#pragma unroll
            for (int i = 0; i < 4; ++i)
#pragma unroll
                for (int j = 0; j < 4; ++j) acc[i][j] = fmaf(a[i], b[j], acc[i][j]);
        }
        if (tt + 1 >= 8) break;
        __syncthreads();
    }
#pragma unroll
    for (int i = 0; i < 4; ++i) {
        int m = m0 + ty * 4 + i;
        *(float4*)&C[(size_t)m * 1024 + n0 + tx * 4] =
            make_float4(acc[i][0], acc[i][1], acc[i][2], acc[i][3]);
    }
}

// ============ scan phase 1: in-block conv+silu+dbc, local chunk scan ============
// grid (NC, NB, 2), 256 thr.
__global__ __launch_bounds__(256) void scan_phase1(
    const float* __restrict__ xz, const float* __restrict__ xpw,
    const float* __restrict__ cw, const float* __restrict__ cb,
    const float* __restrict__ dtw, const float* __restrict__ dtb,
    const float* __restrict__ alog,
    float* __restrict__ dbc_g, float* __restrict__ hpart, float* __restrict__ pprod) {
    const int c = blockIdx.x, b = blockIdx.y, z = blockIdx.z;
    const int tid = threadIdx.x;
    const int d = z * 256 + tid;
    __shared__ float xzS[11][512];
    __shared__ float uS[8][512];
    __shared__ float partS[4][8][48];
    __shared__ float dbcS[8][48];
    // stage xz u-half rows (c*8-3 .. c*8+7), zero-pad below 0
    for (int idx = tid; idx < 11 * 128; idx += 256) {
        int r = idx >> 7, c4 = (idx & 127) << 2;
        int gl = c * 8 - 3 + r;
        float4 v = make_float4(0.f, 0.f, 0.f, 0.f);
        if (gl >= 0) v = *(const float4*)&xz[((size_t)(b * 256 + gl)) * 1024 + c4];
        *(float4*)&xzS[r][c4] = v;
    }
    __syncthreads();
    // u = silu(conv) for all 512 channels x 8 tokens
    for (int i = tid; i < 4096; i += 256) {
        int r = i >> 9, dd = i & 511;
        float4 w4 = *(const float4*)&cw[dd * 4];
        float a = cb[dd];
        a = fmaf(xzS[r + 0][dd], w4.x, a);
        a = fmaf(xzS[r + 1][dd], w4.y, a);
        a = fmaf(xzS[r + 2][dd], w4.z, a);
        a = fmaf(xzS[r + 3][dd], w4.w, a);
        uS[r][dd] = silu_f(a);
    }
    __syncthreads();
    // dbc[r][col] = sum_k u[r][k]*xpw[col][k], k split in 4 quarters over 192 threads
    if (tid < 192) {
        int col = tid % 48, kq = tid / 48;
        const float* wp = xpw + (size_t)col * 512 + kq * 128;
        float accq[8] = {};
        for (int k = 0; k < 128; k += 4) {
            float4 w4 = *(const float4*)&wp[k];
            int kk = kq * 128 + k;
#pragma unroll
            for (int r = 0; r < 8; ++r) {
                float4 u4 = *(const float4*)&uS[r][kk];
                accq[r] = fmaf(u4.x, w4.x, accq[r]);
                accq[r] = fmaf(u4.y, w4.y, accq[r]);
                accq[r] = fmaf(u4.z, w4.z, accq[r]);
                accq[r] = fmaf(u4.w, w4.w, accq[r]);
            }
        }
#pragma unroll
        for (int r = 0; r < 8; ++r) partS[kq][r][col] = accq[r];
    }
    __syncthreads();
    if (tid < 384) {
        int r = tid / 48, col = tid % 48;
        float v = (partS[0][r][col] + partS[1][r][col]) + (partS[2][r][col] + partS[3][r][col]);
        dbcS[r][col] = v;
        if (z == 0) dbc_g[((size_t)(b * 256 + c * 8 + r)) * 48 + col] = v;
    }
    // per-channel params
    float wv[16], Av[16];
#pragma unroll
    for (int s4 = 0; s4 < 16; s4 += 4) {
        float4 t1 = *(const float4*)(dtw + d * 16 + s4);
        wv[s4] = t1.x; wv[s4 + 1] = t1.y; wv[s4 + 2] = t1.z; wv[s4 + 3] = t1.w;
        float4 t2 = *(const float4*)(alog + d * 16 + s4);
        Av[s4] = -expf(t2.x); Av[s4 + 1] = -expf(t2.y);
        Av[s4 + 2] = -expf(t2.z); Av[s4 + 3] = -expf(t2.w);
    }
    float bv = dtb[d];
    float h[16] = {}, P[16];
#pragma unroll
    for (int s = 0; s < 16; ++s) P[s] = 1.0f;
    __syncthreads();
    for (int r = 0; r < CL; ++r) {
        float uv = uS[r][d];
        float pre = bv;
#pragma unroll
        for (int j = 0; j < 16; ++j) pre = fmaf(dbcS[r][j], wv[j], pre);
        float dt = softplus_f(pre);
        float du = dt * uv;
#pragma unroll
        for (int s = 0; s < 16; ++s) {
            float dA = expf(dt * Av[s]);
            h[s] = fmaf(dA, h[s], du * dbcS[r][16 + s]);
            P[s] *= dA;
        }
    }
    size_t base = ((size_t)((b * NC + c) * DI) + d) * 16;
#pragma unroll
    for (int s = 0; s < 16; ++s) { hpart[base + s] = h[s]; pprod[base + s] = P[s]; }
}

// ============ scan phase 2: combine chunk boundary states (linear) ============
// grid 256, block 256: idx = b*8192 + ds over NB*DI*DS = 65536
__global__ void scan_phase2(const float* __restrict__ hpart, const float* __restrict__ pprod,
                            float* __restrict__ hinit) {
    int idx = blockIdx.x * 256 + threadIdx.x;
    int b = idx >> 13, ds = idx & 8191;
    float carry = 0.0f;
    for (int c = 0; c < NC; ++c) {
        size_t a = ((size_t)(b * NC + c)) * (DI * 16) + ds;
        hinit[a] = carry;
        carry = fmaf(pprod[a], carry, hpart[a]);
    }
}

// ============ scan phase 3: replay with hinit, y*silu(z) ============
__global__ __launch_bounds__(256) void scan_phase3(
    const float* __restrict__ xz, const float* __restrict__ dbc_g,
    const float* __restrict__ cw, const float* __restrict__ cb,
    const float* __restrict__ dtw, const float* __restrict__ dtb,
    const float* __restrict__ alog, const float* __restrict__ Dpv,
    const float* __restrict__ hinit, float* __restrict__ yz) {
    const int c = blockIdx.x, b = blockIdx.y, z = blockIdx.z;
    const int tid = threadIdx.x;
    const int d = z * 256 + tid;
    __shared__ float xzS[11][256];
    __shared__ float uS[8][256];
    __shared__ float dbcS[8][48];
    for (int idx = tid; idx < 11 * 64; idx += 256) {
        int r = idx >> 6, c4 = (idx & 63) << 2;
        int gl = c * 8 - 3 + r;
        float4 v = make_float4(0.f, 0.f, 0.f, 0.f);
        if (gl >= 0) v = *(const float4*)&xz[((size_t)(b * 256 + gl)) * 1024 + z * 256 + c4];
        *(float4*)&xzS[r][c4] = v;
    }
    __syncthreads();
    for (int i = tid; i < 2048; i += 256) {
        int r = i >> 8, dd = i & 255;
        float4 w4 = *(const float4*)&cw[(z * 256 + dd) * 4];
        float a = cb[z * 256 + dd];
        a = fmaf(xzS[r + 0][dd], w4.x, a);
        a = fmaf(xzS[r + 1][dd], w4.y, a);
        a = fmaf(xzS[r + 2][dd], w4.z, a);
        a = fmaf(xzS[r + 3][dd], w4.w, a);
        uS[r][dd] = silu_f(a);
    }
    if (tid < 384) {
        int r = tid / 48, col = tid % 48;
        dbcS[r][col] = dbc_g[((size_t)(b * 256 + c * 8 + r)) * 48 + col];
    }
    float wv[16], Av[16];
#pragma unroll
    for (int s4 = 0; s4 < 16; s4 += 4) {
        float4 t1 = *(const float4*)(dtw + d * 16 + s4);
        wv[s4] = t1.x; wv[s4 + 1] = t1.y; wv[s4 + 2] = t1.z; wv[s4 + 3] = t1.w;
        float4 t2 = *(const float4*)(alog + d * 16 + s4);
        Av[s4] = -expf(t2.x); Av[s4 + 1] = -expf(t2.y);
        Av[s4 + 2] = -expf(t2.z); Av[s4 + 3] = -expf(t2.w);
    }
    float bv = dtb[d];
    float Dv = Dpv[d];
    // initial state from phase 2
    float h[16];
    size_t base = ((size_t)((b * NC + c) * DI) + d) * 16;
#pragma unroll
    for (int s4 = 0; s4 < 16; s4 += 4) {
        float4 hv = *(const float4*)&hinit[base + s4];
        h[s4 + 0] = hv.x; h[s4 + 1] = hv.y; h[s4 + 2] = hv.z; h[s4 + 3] = hv.w;
    }
    const float* zrow = xz + ((size_t)(b * 256 + c * 8)) * 1024 + 512 + d;
    float* yrow = yz + ((size_t)(b * 256 + c * 8)) * 512 + d;
    __syncthreads();
    for (int r = 0; r < CL; ++r) {
        float uv = uS[r][tid];
        float pre = bv;
#pragma unroll
        for (int j = 0; j < 16; ++j) pre = fmaf(dbcS[r][j], wv[j], pre);
        float dt = softplus_f(pre);
        float du = dt * uv;
        float y = uv * Dv;
#pragma unroll
        for (int s = 0; s < 16; ++s) {
            float dA = expf(dt * Av[s]);
            h[s] = fmaf(dA, h[s], du * dbcS[r][16 + s]);
            y = fmaf(h[s], dbcS[r][32 + s], y);
        }
        float zv = zrow[r * 1024];
        yrow[r * 512] = y * silu_f(zv);
    }
}

// ============ out_proj GEMM, atomic accumulate into H (residual) ============
// grid (4, 32, 4). K=512 split 4 (128/slice). A=YZ (2048x512), B=opw (256x512).
__global__ __launch_bounds__(256) void outproj_gemm(
    const float* __restrict__ A, const float* __restrict__ Bw,
    float* __restrict__ Hout) {
    const int tid = threadIdx.x;
    const int n0 = blockIdx.x * 64, m0 = blockIdx.y * 64;
    const int kbase = blockIdx.z * 128;
    __shared__ float As[32][68];
    __shared__ float Bs[32][68];
    const int tx = tid & 15, ty = tid >> 4;
    const int srow = tid >> 3, sk4 = tid & 7;
    const float* Ap0 = A + (size_t)(m0 + srow) * 512 + kbase + sk4 * 4;
    const float* Ap1 = Ap0 + (size_t)32 * 512;
    const float* Bp0 = Bw + (size_t)(n0 + srow) * 512 + kbase + sk4 * 4;
    const float* Bp1 = Bp0 + (size_t)32 * 512;
    float4 pa0 = *(const float4*)Ap0, pa1 = *(const float4*)Ap1;
    float4 pb0 = *(const float4*)Bp0, pb1 = *(const float4*)Bp1;
    float acc[4][4] = {};
    for (int tt = 0;; ++tt) {
        As[sk4 * 4 + 0][srow] = pa0.x;  As[sk4 * 4 + 1][srow] = pa0.y;
        As[sk4 * 4 + 2][srow] = pa0.z;  As[sk4 * 4 + 3][srow] = pa0.w;
        As[sk4 * 4 + 0][srow + 32] = pa1.x;  As[sk4 * 4 + 1][srow + 32] = pa1.y;
        As[sk4 * 4 + 2][srow + 32] = pa1.z;  As[sk4 * 4 + 3][srow + 32] = pa1.w;
        Bs[sk4 * 4 + 0][srow] = pb0.x;  Bs[sk4 * 4 + 1][srow] = pb0.y;
        Bs[sk4 * 4 + 2][srow] = pb0.z;  Bs[sk4 * 4 + 3][srow] = pb0.w;
        Bs[sk4 * 4 + 0][srow + 32] = pb1.x;  Bs[sk4 * 4 + 1][srow + 32] = pb1.y;
        Bs[sk4 * 4 + 2][srow + 32] = pb1.z;  Bs[sk4 * 4 + 3][srow + 32] = pb1.w;
        __syncthreads();
        if (tt + 1 < 4) {
            int off = (tt + 1) * 32;
            pa0 = *(const float4*)(Ap0 + off);
            pa1 = *(const float4*)(Ap1 + off);
            pb0 = *(const float4*)(Bp0 + off);
            pb1 = *(const float4*)(Bp1 + off);
        }
#pragma unroll
        for (int kk = 0; kk < 32; ++kk) {
            float4 av = *(const float4*)&As[kk][ty * 4];
            float4 bv = *(const float4*)&Bs[kk][tx * 4];
            float a[4] = {av.x, av.y, av.z, av.w};
            float b[4] = {bv.x, bv.y, bv.z, bv.w};
#pragma unroll
            for (int i = 0; i < 4; ++i)
#pragma unroll
                for (int j = 0; j < 4; ++j) acc[i][j] = fmaf(a[i], b[j], acc[i][j]);
        }
        if (tt + 1 >= 4) break;
        __syncthreads();
    }
#pragma unroll
    for (int i = 0; i < 4; ++i) {
        int m = m0 + ty * 4 + i;
#pragma unroll
        for (int j = 0; j < 4; ++j)
            atomicAdd(&Hout[(size_t)m * 256 + n0 + tx * 4 + j], acc[i][j]);
    }
}

// ============ decoder convT 2x2 s2 as GEMM + bias + gelu (dec1, dec2) ============
template <int BM, bool AROW>
__global__ __launch_bounds__(256) void convt_gemm(
    const float* __restrict__ A, const float* __restrict__ Wt, const float* __restrict__ bias,
    float* __restrict__ out, int K, int N, int HW, int Wdim, int O) {
    constexpr int TM = BM / 16;
    const int tid = threadIdx.x;
    const int n0 = blockIdx.x * 64;
    const int m0 = blockIdx.y * BM;
    __shared__ float As[32][BM + 4];
    __shared__ float Bs[32][68];
    const int tx = tid & 15, ty = tid >> 4;
    float acc[TM][4] = {};
    const int T = K >> 5;
    float4 pa0, pa1;
    float pra[BM / 8];
    float prb[8];
    const int srow = tid >> 3, sk4 = tid & 7;
    const float* Ap0 = nullptr; const float* Ap1 = nullptr; const float* Ab = nullptr;
    if constexpr (AROW) {
        Ap0 = A + (size_t)(m0 + srow) * K + sk4 * 4;
        Ap1 = Ap0 + (size_t)32 * K;
        pa0 = *(const float4*)Ap0;
        if constexpr (BM == 64) pa1 = *(const float4*)Ap1;
    } else {
        int bb = m0 / HW, hw0 = m0 % HW;
        Ab = A + ((size_t)bb * K) * HW + hw0;
#pragma unroll
        for (int f = 0; f < BM / 8; ++f)
            pra[f] = Ab[(size_t)((tid >> 6) + 4 * f) * HW + (tid & 63)];
    }
#pragma unroll
    for (int f = 0; f < 8; ++f)
        prb[f] = Wt[(size_t)((tid >> 6) + 4 * f) * N + n0 + (tid & 63)];
    for (int t = 0;; ++t) {
        if constexpr (AROW) {
            As[sk4 * 4 + 0][srow] = pa0.x;  As[sk4 * 4 + 1][srow] = pa0.y;
            As[sk4 * 4 + 2][srow] = pa0.z;  As[sk4 * 4 + 3][srow] = pa0.w;
            if constexpr (BM == 64) {
                As[sk4 * 4 + 0][srow + 32] = pa1.x;  As[sk4 * 4 + 1][srow + 32] = pa1.y;
                As[sk4 * 4 + 2][srow + 32] = pa1.z;  As[sk4 * 4 + 3][srow + 32] = pa1.w;
            }
        } else {
#pragma unroll
            for (int f = 0; f < BM / 8; ++f)
                As[(tid >> 6) + 4 * f][tid & 63] = pra[f];
        }
#pragma unroll
        for (int f = 0; f < 8; ++f)
            Bs[(tid >> 6) + 4 * f][tid & 63] = prb[f];
        __syncthreads();
        if (t + 1 < T) {
            int off = (t + 1) * 32;
            if constexpr (AROW) {
                pa0 = *(const float4*)(Ap0 + off);
                if constexpr (BM == 64) pa1 = *(const float4*)(Ap1 + off);
            } else {
#pragma unroll
                for (int f = 0; f < BM / 8; ++f)
                    pra[f] = Ab[(size_t)(off + (tid >> 6) + 4 * f) * HW + (tid & 63)];
            }
#pragma unroll
            for (int f = 0; f < 8; ++f)
                prb[f] = Wt[(size_t)(off + (tid >> 6) + 4 * f) * N + n0 + (tid & 63)];
        }
#pragma unroll
        for (int kk = 0; kk < 32; ++kk) {
            float a[TM];
#pragma unroll
            for (int i = 0; i < TM; ++i) a[i] = As[kk][ty * TM + i];
            float4 bv = *(const float4*)&Bs[kk][tx * 4];
            float b[4] = {bv.x, bv.y, bv.z, bv.w};
#pragma unroll
            for (int i = 0; i < TM; ++i)
#pragma unroll
                for (int j = 0; j < 4; ++j) acc[i][j] = fmaf(a[i], b[j], acc[i][j]);
        }
        if (t + 1 >= T) break;
        __syncthreads();
    }
    int Hdim = HW / Wdim;
#pragma unroll
    for (int i = 0; i < TM; ++i) {
        int m = m0 + ty * TM + i;
        int b = m / HW, hw = m % HW;
        int hh = hw / Wdim, ww = hw % Wdim;
#pragma unroll
        for (int j = 0; j < 4; ++j) {
            int n = n0 + tx * 4 + j;
            int o = n >> 2, p = (n >> 1) & 1, q = n & 1;
            out[(((size_t)(b * O + o)) * (2 * Hdim) + 2 * hh + p) * (size_t)(2 * Wdim) + 2 * ww + q] =
                gelu_f(acc[i][j] + bias[o]);
        }
    }
}

// ============ dec3 (K=64 -> 32ch,2x2) fused with dec4 (32ch -> 1ch,2x2) ============
// grid 1024 blocks, 256 thr. A = D2 (8,64,64,64) k-major; BM=32 pixels, BN=128 (full).
__global__ __launch_bounds__(256) void dec34_kernel(
    const float* __restrict__ A, const float* __restrict__ W3, const float* __restrict__ b3,
    const float* __restrict__ w4, const float* __restrict__ b4,
    float* __restrict__ out) {
    const int tid = threadIdx.x;
    const int m0 = blockIdx.x * 32;
    __shared__ float As[32][36];
    __shared__ float Bs[32][132];
    __shared__ float d3S[32][4][33];
    __shared__ float w4S[128];
    if (tid < 128) w4S[tid] = w4[tid];
    const int tx = tid & 15, ty = tid >> 4;
    float acc[2][8] = {};
    int bb = m0 >> 12, hw0 = m0 & 4095;
    const float* Ab = A + ((size_t)bb * 64) * 4096 + hw0;
    for (int t = 0; t < 2; ++t) {
        int k0 = t * 32;
        for (int idx = tid; idx < 1024; idx += 256) {
            int kk = idx >> 5, mm = idx & 31;
            As[kk][mm] = Ab[(size_t)(k0 + kk) * 4096 + mm];
        }
        for (int idx = tid; idx < 4096; idx += 256) {
            int kk = idx >> 7, nn = idx & 127;
            Bs[kk][nn] = W3[(size_t)(k0 + kk) * 128 + nn];
        }
        __syncthreads();
#pragma unroll
        for (int kk = 0; kk < 32; ++kk) {
            float a0 = As[kk][ty * 2 + 0];
            float a1 = As[kk][ty * 2 + 1];
            float4 b0 = *(const float4*)&Bs[kk][tx * 8];
            float4 b1 = *(const float4*)&Bs[kk][tx * 8 + 4];
            float bb8[8] = {b0.x, b0.y, b0.z, b0.w, b1.x, b1.y, b1.z, b1.w};
#pragma unroll
            for (int j = 0; j < 8; ++j) {
                acc[0][j] = fmaf(a0, bb8[j], acc[0][j]);
                acc[1][j] = fmaf(a1, bb8[j], acc[1][j]);
            }
        }
        __syncthreads();
    }
    // d3 tile (gelu) into LDS: d3S[pixel][pq][channel]
#pragma unroll
    for (int i = 0; i < 2; ++i) {
        int m_loc = ty * 2 + i;
#pragma unroll
        for (int j = 0; j < 8; ++j) {
            int n = tx * 8 + j;
            int o = n >> 2, pq = n & 3;
            d3S[m_loc][pq][o] = gelu_f(acc[i][j] + b3[o]);
        }
    }
    __syncthreads();
    // dec4: each d3 pixel -> 4 final outputs
    float bias4 = b4[0];
#pragma unroll
    for (int it = 0; it < 2; ++it) {
        int oi = tid + 256 * it;
        int m_loc = oi >> 4, rem = oi & 15, pq = rem >> 2, pq2 = rem & 3;
        float s = bias4;
#pragma unroll
        for (int cch = 0; cch < 32; ++cch)
            s = fmaf(d3S[m_loc][pq][cch], w4S[cch * 4 + pq2], s);
        int m_glob = m0 + m_loc;
        int b = m_glob >> 12, hw = m_glob & 4095, hh = hw >> 6, ww = hw & 63;
        int H128 = 2 * hh + (pq >> 1), W128 = 2 * ww + (pq & 1);
        int row = 2 * H128 + (pq2 >> 1), col = 2 * W128 + (pq2 & 1);
        out[(size_t)b * 65536 + (size_t)row * 256 + col] = s;
    }
}

// ---------------- workspace layout (floats) ----------------
#define H_OFF     ((size_t)0)          // 524288
#define TEMB_OFF  ((size_t)524288)     // 2048
#define PART_OFF  ((size_t)526336)     // 4 x 524288 = 2097152 (HINIT aliases this)
#define XZ_OFF    ((size_t)2623488)    // 2097152
#define YZ_OFF    ((size_t)4720640)    // 1048576
#define DBC_OFF   ((size_t)5769216)    // 98304
#define HPART_OFF ((size_t)5867520)    // 2097152
#define PPROD_OFF ((size_t)7964672)    // 2097152  (end 10061824)

extern "C" void kernel_launch(void* const* d_in, const int* in_sizes, int n_in,
                              void* d_out, int out_size, void* d_ws, size_t ws_size,
                              hipStream_t stream) {
    (void)in_sizes; (void)n_in; (void)out_size; (void)ws_size;
    const float* x    = (const float*)d_in[0];
    const int*   t    = (const int*)d_in[1];
    const float* tw1  = (const float*)d_in[2];
    const float* tb1  = (const float*)d_in[3];
    const float* tw2  = (const float*)d_in[4];
    const float* tb2  = (const float*)d_in[5];
    const float* pw   = (const float*)d_in[6];
    const float* pb   = (const float*)d_in[7];
    const float* pos  = (const float*)d_in[8];
    const float* lng  = (const float*)d_in[9];
    const float* lnb  = (const float*)d_in[10];
    const float* ipw  = (const float*)d_in[11];
    const float* cw   = (const float*)d_in[12];
    const float* cb   = (const float*)d_in[13];
    const float* xpw  = (const float*)d_in[14];
    const float* dtw  = (const float*)d_in[15];
    const float* dtb  = (const float*)d_in[16];
    const float* alog = (const float*)d_in[17];
    const float* Dp   = (const float*)d_in[18];
    const float* opw  = (const float*)d_in[19];
    const float* dw1  = (const float*)d_in[20];
    const float* db1  = (const float*)d_in[21];
    const float* dw2  = (const float*)d_in[22];
    const float* db2  = (const float*)d_in[23];
    const float* dw3  = (const float*)d_in[24];
    const float* db3  = (const float*)d_in[25];
    const float* dw4  = (const float*)d_in[26];
    const float* db4  = (const float*)d_in[27];

    float* ws    = (float*)d_ws;
    float* H     = ws + H_OFF;
    float* TEMB  = ws + TEMB_OFF;
    float* PART  = ws + PART_OFF;
    float* XZ    = ws + XZ_OFF;
    float* YZ    = ws + YZ_OFF;
    float* DBC   = ws + DBC_OFF;
    float* HPART = ws + HPART_OFF;
    float* PPROD = ws + PPROD_OFF;
    float* HINIT = PART;    // PART is dead after combine_patch
    float* D1    = YZ;      // lifetime disjoint
    float* D2    = HPART;   // lifetime disjoint

    patch_gemm<<<dim3(4, 32, 4), 256, 0, stream>>>(x, pw, t, tw1, tb1, tw2, tb2, PART, TEMB);
    combine_patch<<<2048, 256, 0, stream>>>(PART, pb, pos, TEMB, H);

    for (int i = 0; i < 8; ++i) {
        in_proj_ln<<<dim3(16, 32), 256, 0, stream>>>(
            H, ipw + (size_t)i * 262144, lng + (size_t)i * 256, lnb + (size_t)i * 256, XZ);
        scan_phase1<<<dim3(NC, NB, 2), 256, 0, stream>>>(
            XZ, xpw + (size_t)i * 24576, cw + (size_t)i * 2048, cb + (size_t)i * 512,
            dtw + (size_t)i * 8192, dtb + (size_t)i * 512, alog + (size_t)i * 8192,
            DBC, HPART, PPROD);
        scan_phase2<<<256, 256, 0, stream>>>(HPART, PPROD, HINIT);
        scan_phase3<<<dim3(NC, NB, 2), 256, 0, stream>>>(
            XZ, DBC, cw + (size_t)i * 2048, cb + (size_t)i * 512,
            dtw + (size_t)i * 8192, dtb + (size_t)i * 512, alog + (size_t)i * 8192,
            Dp + (size_t)i * 512, HINIT, YZ);
        outproj_gemm<<<dim3(4, 32, 4), 256, 0, stream>>>(YZ, opw + (size_t)i * 131072, H);
    }

    // decoder
    convt_gemm<32, true><<<dim3(8, 64), 256, 0, stream>>>(H, dw1, db1, D1, 256, 512, 256, 16, 128);
    convt_gemm<64, false><<<dim3(4, 128), 256, 0, stream>>>(D1, dw2, db2, D2, 128, 256, 1024, 32, 64);
    dec34_kernel<<<1024, 256, 0, stream>>>(D2, dw3, db3, dw4, db4, (float*)d_out);
}